// Round 1
// baseline (997.836 us; speedup 1.0000x reference)
//
#include <hip/hip_runtime.h>
#include <hip/hip_bf16.h>
#include <math.h>

#define NDIM 128
#define EDIM 64
#define DDIM 256
#define TILE 16

// ---------------------------------------------------------------------------
// Edge aggregation: agg[n,:] = sum of edge_attr over edges with row==n,
// cnt[n] = number of such edges. 16 threads per edge, float4 loads.
// ---------------------------------------------------------------------------
__global__ __launch_bounds__(256) void k_edge_agg(
    const float* __restrict__ edge_attr, const int* __restrict__ erow,
    float* __restrict__ agg, float* __restrict__ cnt, int E)
{
    int gid = blockIdx.x * 256 + threadIdx.x;
    int e = gid >> 4;
    int seg = gid & 15;
    if (e >= E) return;
    int r = erow[e];
    const float4 a = *reinterpret_cast<const float4*>(edge_attr + (size_t)e * EDIM + seg * 4);
    float* dst = agg + (size_t)r * EDIM + seg * 4;
    atomicAdd(dst + 0, a.x);
    atomicAdd(dst + 1, a.y);
    atomicAdd(dst + 2, a.z);
    atomicAdd(dst + 3, a.w);
    if (seg == 0) atomicAdd(cnt + r, 1.0f);
}

// ---------------------------------------------------------------------------
// Transpose node_w (256x128 -> 128x256) and edge_w (256x64 -> 64x256) so the
// projection kernel reads weights coalesced.
// ---------------------------------------------------------------------------
__global__ __launch_bounds__(256) void k_transpose(
    const float* __restrict__ node_w, const float* __restrict__ edge_w,
    float* __restrict__ node_wT, float* __restrict__ edge_wT)
{
    int idx = blockIdx.x * 256 + threadIdx.x;
    if (idx < DDIM * NDIM) {
        int k = idx / DDIM, j = idx % DDIM;
        node_wT[idx] = node_w[j * NDIM + k];
    }
    if (idx < DDIM * EDIM) {
        int k = idx / DDIM, j = idx % DDIM;
        edge_wT[idx] = edge_w[j * EDIM + k];
    }
}

// ---------------------------------------------------------------------------
// Tiny prep: q = query @ wq.T + bq (256), then qk[h,:] = sum_d q[h,d]*wk[h*64+d,:]
// (4x256) and sb[h] = sum_d q[h,d]*bk[h*64+d].
// ---------------------------------------------------------------------------
__global__ __launch_bounds__(256) void k_prep(
    const float* __restrict__ query, const float* __restrict__ in_w,
    const float* __restrict__ in_b, float* __restrict__ qk, float* __restrict__ sb)
{
    __shared__ float q_s[DDIM];
    __shared__ float qv[DDIM];
    int tid = threadIdx.x;
    q_s[tid] = query[tid];
    __syncthreads();
    float acc = in_b[tid];
    const float* wq = in_w + (size_t)tid * DDIM;
    for (int i = 0; i < DDIM; ++i) acc += q_s[i] * wq[i];
    qv[tid] = acc;
    __syncthreads();
    for (int h = 0; h < 4; ++h) {
        float a = 0.f;
        for (int d = 0; d < 64; ++d)
            a += qv[h * 64 + d] * in_w[(size_t)(DDIM + h * 64 + d) * DDIM + tid];
        qk[h * DDIM + tid] = a;
    }
    if (tid < 4) {
        float a = 0.f;
        for (int d = 0; d < 64; ++d) a += qv[tid * 64 + d] * in_b[DDIM + tid * 64 + d];
        sb[tid] = a;
    }
}

// ---------------------------------------------------------------------------
// Fused projection + scores.
// h_proj[n,:] = h[n]@node_w.T + node_b + (agg[n]@edge_w.T)/max(cnt,1)
//               + edge_b*(cnt>0)
// scores[n,h] = (h_proj[n]·qk[h] + sb[h]) / 8
// Block: 256 threads, TILE=16 nodes. Thread (dg=tid&63, ng=tid>>6) computes
// dims 4dg..4dg+3 for nodes 4ng..4ng+3 (register-blocked 4x4).
// Wave == node-group, so LDS h reads are same-address broadcasts.
// ---------------------------------------------------------------------------
__global__ __launch_bounds__(256) void k_proj(
    const float* __restrict__ h, const float* __restrict__ agg, const float* __restrict__ cnt,
    const float* __restrict__ node_wT, const float* __restrict__ edge_wT,
    const float* __restrict__ node_b, const float* __restrict__ edge_b,
    const float* __restrict__ qk, const float* __restrict__ sb,
    float* __restrict__ h_proj, float* __restrict__ scores, int N)
{
    __shared__ float h_s[TILE][NDIM + 4];   // pad -> row stride 132 (16B aligned)
    __shared__ float a_s[TILE][EDIM + 4];   // stride 68
    __shared__ float qk_s[4 * DDIM];
    __shared__ float ps[64][68];            // [dg][t*4+h] score partials
    __shared__ float ps2[4][64];
    __shared__ float cnt_s[TILE];
    __shared__ float sb_s[4];

    const int tid = threadIdx.x;
    const int n0 = blockIdx.x * TILE;

    for (int i = tid; i < 4 * DDIM; i += 256) qk_s[i] = qk[i];
    if (tid < 4) sb_s[tid] = sb[tid];
    if (tid < TILE) cnt_s[tid] = (n0 + tid < N) ? cnt[n0 + tid] : 0.f;

    for (int i = tid; i < TILE * (NDIM / 4); i += 256) {
        int t = i / (NDIM / 4), kq = i % (NDIM / 4);
        float4 v = make_float4(0.f, 0.f, 0.f, 0.f);
        if (n0 + t < N) v = reinterpret_cast<const float4*>(h + (size_t)(n0 + t) * NDIM)[kq];
        *reinterpret_cast<float4*>(&h_s[t][kq * 4]) = v;
    }
    for (int i = tid; i < TILE * (EDIM / 4); i += 256) {
        int t = i / (EDIM / 4), kq = i % (EDIM / 4);
        float4 v = make_float4(0.f, 0.f, 0.f, 0.f);
        if (n0 + t < N) v = reinterpret_cast<const float4*>(agg + (size_t)(n0 + t) * EDIM)[kq];
        *reinterpret_cast<float4*>(&a_s[t][kq * 4]) = v;
    }
    __syncthreads();

    const int dg = tid & 63;
    const int ng = tid >> 6;
    const int j0 = dg * 4;

    float acc[4][4];
    float acc2[4][4];
#pragma unroll
    for (int t = 0; t < 4; ++t)
#pragma unroll
        for (int j = 0; j < 4; ++j) { acc[t][j] = 0.f; acc2[t][j] = 0.f; }

    // node_w contribution (K = 128)
    for (int k0 = 0; k0 < NDIM; k0 += 4) {
        float w[4][4];
#pragma unroll
        for (int kk = 0; kk < 4; ++kk) {
            float4 wv = *reinterpret_cast<const float4*>(node_wT + (size_t)(k0 + kk) * DDIM + j0);
            w[kk][0] = wv.x; w[kk][1] = wv.y; w[kk][2] = wv.z; w[kk][3] = wv.w;
        }
#pragma unroll
        for (int t = 0; t < 4; ++t) {
            float4 hv = *reinterpret_cast<const float4*>(&h_s[ng * 4 + t][k0]);
#pragma unroll
            for (int j = 0; j < 4; ++j)
                acc[t][j] += hv.x * w[0][j] + hv.y * w[1][j] + hv.z * w[2][j] + hv.w * w[3][j];
        }
    }
    // edge contribution (K = 64)
    for (int k0 = 0; k0 < EDIM; k0 += 4) {
        float w[4][4];
#pragma unroll
        for (int kk = 0; kk < 4; ++kk) {
            float4 wv = *reinterpret_cast<const float4*>(edge_wT + (size_t)(k0 + kk) * DDIM + j0);
            w[kk][0] = wv.x; w[kk][1] = wv.y; w[kk][2] = wv.z; w[kk][3] = wv.w;
        }
#pragma unroll
        for (int t = 0; t < 4; ++t) {
            float4 av = *reinterpret_cast<const float4*>(&a_s[ng * 4 + t][k0]);
#pragma unroll
            for (int j = 0; j < 4; ++j)
                acc2[t][j] += av.x * w[0][j] + av.y * w[1][j] + av.z * w[2][j] + av.w * w[3][j];
        }
    }

    float4 nb4 = *reinterpret_cast<const float4*>(node_b + j0);
    float4 eb4 = *reinterpret_cast<const float4*>(edge_b + j0);
    float nb[4] = {nb4.x, nb4.y, nb4.z, nb4.w};
    float eb[4] = {eb4.x, eb4.y, eb4.z, eb4.w};

    float hp[4][4];
#pragma unroll
    for (int t = 0; t < 4; ++t) {
        float c = cnt_s[ng * 4 + t];
        float inv = 1.f / fmaxf(c, 1.f);
        float fl = (c >= 0.5f) ? 1.f : 0.f;
#pragma unroll
        for (int j = 0; j < 4; ++j)
            hp[t][j] = acc[t][j] + nb[j] + acc2[t][j] * inv + eb[j] * fl;
    }

    // store h_proj
#pragma unroll
    for (int t = 0; t < 4; ++t) {
        int n = n0 + ng * 4 + t;
        if (n < N) {
            float4 v = make_float4(hp[t][0], hp[t][1], hp[t][2], hp[t][3]);
            *reinterpret_cast<float4*>(h_proj + (size_t)n * DDIM + j0) = v;
        }
    }

    // score partials: p[t][h] = sum_jj hp[t][jj] * qk[h][j0+jj]
    float4 qk4[4];
#pragma unroll
    for (int hh = 0; hh < 4; ++hh)
        qk4[hh] = *reinterpret_cast<const float4*>(&qk_s[hh * DDIM + j0]);
#pragma unroll
    for (int t = 0; t < 4; ++t) {
        float p[4];
#pragma unroll
        for (int hh = 0; hh < 4; ++hh) {
            float4 q4 = qk4[hh];
            p[hh] = hp[t][0] * q4.x + hp[t][1] * q4.y + hp[t][2] * q4.z + hp[t][3] * q4.w;
        }
        *reinterpret_cast<float4*>(&ps[dg][(ng * 4 + t) * 4]) =
            make_float4(p[0], p[1], p[2], p[3]);
    }
    __syncthreads();

    {
        int grp = tid >> 6;   // 0..3: which 16 dg-columns to sum
        int th = tid & 63;    // (t,h) pair
        float ssum = 0.f;
#pragma unroll
        for (int i = 0; i < 16; ++i) ssum += ps[grp * 16 + i][th];
        ps2[grp][th] = ssum;
    }
    __syncthreads();
    if (tid < 64) {
        float tot = ps2[0][tid] + ps2[1][tid] + ps2[2][tid] + ps2[3][tid];
        int t = tid >> 2, hh = tid & 3;
        int n = n0 + t;
        if (n < N) scores[(size_t)n * 4 + hh] = (tot + sb_s[hh]) * 0.125f;
    }
}

// ---------------------------------------------------------------------------
// Per-graph online-softmax pooling + output GEMM. One block per graph.
// batch is sorted; node range found by binary search. Chunked (256 nodes)
// online softmax; hbar[h][tid] accumulated in registers; then
// pooled = hbar/denom @ wv.T + bv, out = pooled @ out_w.T + out_b.
// ---------------------------------------------------------------------------
__global__ __launch_bounds__(256) void k_pool(
    const float* __restrict__ h_proj, const float* __restrict__ scores,
    const int* __restrict__ batch, const float* __restrict__ in_w,
    const float* __restrict__ in_b, const float* __restrict__ out_w,
    const float* __restrict__ out_b, float* __restrict__ out, int N)
{
    __shared__ float sc_s[256 * 4];
    __shared__ float red_s[16];
    __shared__ float hb_s[4 * DDIM];

    const int g = blockIdx.x;
    const int tid = threadIdx.x;
    const int lane = tid & 63;
    const int wave = tid >> 6;

    int lo = 0, hi = N;
    while (lo < hi) { int mid = (lo + hi) >> 1; if (batch[mid] < g) lo = mid + 1; else hi = mid; }
    const int s = lo;
    hi = N;
    while (lo < hi) { int mid = (lo + hi) >> 1; if (batch[mid] < g + 1) lo = mid + 1; else hi = mid; }
    const int e = lo;

    float m[4], dn[4], hb[4];
#pragma unroll
    for (int hh = 0; hh < 4; ++hh) { m[hh] = -INFINITY; dn[hh] = 0.f; hb[hh] = 0.f; }

    const int h = tid & 3;

    for (int c = s; c < e; c += 256) {
        int cn = min(256, e - c);
        __syncthreads();  // protect sc_s against previous-chunk readers
        if (tid < cn)
            *reinterpret_cast<float4*>(&sc_s[tid * 4]) =
                *reinterpret_cast<const float4*>(scores + (size_t)(c + tid) * 4);
        __syncthreads();

        // chunk max per head
        float lm = -INFINITY;
        for (int n = tid >> 2; n < cn; n += 64) lm = fmaxf(lm, sc_s[n * 4 + h]);
#pragma unroll
        for (int off = 4; off < 64; off <<= 1) lm = fmaxf(lm, __shfl_xor(lm, off));
        if (lane < 4) red_s[wave * 4 + lane] = lm;
        __syncthreads();

        float nm[4];
#pragma unroll
        for (int hh = 0; hh < 4; ++hh) {
            float cm = fmaxf(fmaxf(red_s[hh], red_s[4 + hh]),
                             fmaxf(red_s[8 + hh], red_s[12 + hh]));
            nm[hh] = fmaxf(m[hh], cm);
            float sc = expf(m[hh] - nm[hh]);  // m=-inf on first chunk -> 0
            dn[hh] *= sc; hb[hh] *= sc; m[hh] = nm[hh];
        }
        __syncthreads();  // everyone done reading red_s

        // w = exp(score - m), in place; per-thread denom partial (h fixed)
        float mh = (h == 0) ? nm[0] : (h == 1) ? nm[1] : (h == 2) ? nm[2] : nm[3];
        float ld = 0.f;
        for (int idx = tid; idx < cn * 4; idx += 256) {
            float w = expf(sc_s[idx] - mh);
            sc_s[idx] = w;
            ld += w;
        }
#pragma unroll
        for (int off = 4; off < 64; off <<= 1) ld += __shfl_xor(ld, off);
        __syncthreads();  // sc_s writes visible before hbar phase
        if (lane < 4) red_s[wave * 4 + lane] = ld;
        __syncthreads();
#pragma unroll
        for (int hh = 0; hh < 4; ++hh)
            dn[hh] += red_s[hh] + red_s[4 + hh] + red_s[8 + hh] + red_s[12 + hh];

        // hbar accumulation: hb[h] += w[n,h] * h_proj[n, tid]
#pragma unroll 4
        for (int n = 0; n < cn; ++n) {
            float val = h_proj[(size_t)(c + n) * DDIM + tid];
            float4 w4 = *reinterpret_cast<const float4*>(&sc_s[n * 4]);
            hb[0] += w4.x * val;
            hb[1] += w4.y * val;
            hb[2] += w4.z * val;
            hb[3] += w4.w * val;
        }
    }

    __syncthreads();
    const float has = (e > s) ? 1.f : 0.f;
#pragma unroll
    for (int hh = 0; hh < 4; ++hh)
        hb_s[hh * DDIM + tid] = hb[hh] / fmaxf(dn[hh], 1e-30f);
    __syncthreads();

    // pooled[tid] = hbar[head(tid)] · wv_row(tid) + bv[tid]  (wv = in_w[2D:3D])
    const int jh = tid >> 6;  // head of output dim (uniform per wave)
    const float* wv_row = in_w + (size_t)(2 * DDIM + tid) * DDIM;
    const float* hbr = &hb_s[jh * DDIM];
    float p = 0.f;
    for (int i = 0; i < DDIM; i += 4) {
        float4 a = *reinterpret_cast<const float4*>(hbr + i);
        float4 b = *reinterpret_cast<const float4*>(wv_row + i);
        p += a.x * b.x + a.y * b.y + a.z * b.z + a.w * b.w;
    }
    p = (p + in_b[2 * DDIM + tid]) * has;
    sc_s[tid] = p;
    __syncthreads();

    const float* ow_row = out_w + (size_t)tid * DDIM;
    float o = out_b[tid];
    for (int i = 0; i < DDIM; i += 4) {
        float4 a = *reinterpret_cast<const float4*>(&sc_s[i]);
        float4 b = *reinterpret_cast<const float4*>(ow_row + i);
        o += a.x * b.x + a.y * b.y + a.z * b.z + a.w * b.w;
    }
    out[(size_t)g * DDIM + tid] = o;
}

// ---------------------------------------------------------------------------
extern "C" void kernel_launch(void* const* d_in, const int* in_sizes, int n_in,
                              void* d_out, int out_size, void* d_ws, size_t ws_size,
                              hipStream_t stream) {
    const float* h         = (const float*)d_in[0];
    const int*   edge_idx  = (const int*)d_in[1];
    const float* edge_attr = (const float*)d_in[2];
    const int*   batch     = (const int*)d_in[3];
    const float* node_w    = (const float*)d_in[5];
    const float* node_b    = (const float*)d_in[6];
    const float* edge_w    = (const float*)d_in[7];
    const float* edge_b    = (const float*)d_in[8];
    const float* query     = (const float*)d_in[9];
    const float* in_w      = (const float*)d_in[10];
    const float* in_b      = (const float*)d_in[11];
    const float* out_w     = (const float*)d_in[12];
    const float* out_b     = (const float*)d_in[13];
    float* out = (float*)d_out;

    const int N = in_sizes[0] / NDIM;
    const int E = in_sizes[2] / EDIM;
    const int G = out_size / DDIM;

    float* ws = (float*)d_ws;
    size_t off = 0;
    float* agg     = ws + off; off += (size_t)N * EDIM;
    float* cnt     = ws + off; off += (size_t)N;
    float* h_proj  = ws + off; off += (size_t)N * DDIM;
    float* scores  = ws + off; off += (size_t)N * 4;
    float* node_wT = ws + off; off += (size_t)DDIM * NDIM;
    float* edge_wT = ws + off; off += (size_t)DDIM * EDIM;
    float* qk      = ws + off; off += 4 * DDIM;
    float* sb      = ws + off; off += 16;

    hipMemsetAsync(agg, 0, (size_t)N * EDIM * sizeof(float), stream);
    hipMemsetAsync(cnt, 0, (size_t)N * sizeof(float), stream);

    {
        int total = E * 16;
        k_edge_agg<<<(total + 255) / 256, 256, 0, stream>>>(edge_attr, edge_idx, agg, cnt, E);
    }
    k_transpose<<<(DDIM * NDIM + 255) / 256, 256, 0, stream>>>(node_w, edge_w, node_wT, edge_wT);
    k_prep<<<1, 256, 0, stream>>>(query, in_w, in_b, qk, sb);
    k_proj<<<(N + TILE - 1) / TILE, 256, 0, stream>>>(
        h, agg, cnt, node_wT, edge_wT, node_b, edge_b, qk, sb, h_proj, scores, N);
    k_pool<<<G, 256, 0, stream>>>(h_proj, scores, batch, in_w, in_b, out_w, out_b, out, N);
}

// Round 2
// 415.412 us; speedup vs baseline: 2.4020x; 2.4020x over previous
//
#include <hip/hip_runtime.h>
#include <hip/hip_bf16.h>
#include <math.h>

#define NDIM 128
#define EDIM 64
#define DDIM 256
#define TILE 16

// ---------------------------------------------------------------------------
// Edge binning pipeline (replaces float-atomic scatter-add):
// hist -> scan -> scatter(perm) -> per-node segmented reduce (no f32 atomics)
// ---------------------------------------------------------------------------
__global__ __launch_bounds__(256) void k_hist(
    const int* __restrict__ erow, int* __restrict__ cnt_i, int E)
{
    int e = blockIdx.x * 256 + threadIdx.x;
    if (e < E) atomicAdd(&cnt_i[erow[e]], 1);
}

// block-of-1024-elements partial sums
__global__ __launch_bounds__(256) void k_scan1(
    const int* __restrict__ cnt_i, int* __restrict__ blocksum, int N)
{
    int tid = threadIdx.x;
    int i0 = blockIdx.x * 1024 + tid * 4;
    int s = 0;
#pragma unroll
    for (int k = 0; k < 4; ++k) { int i = i0 + k; if (i < N) s += cnt_i[i]; }
#pragma unroll
    for (int off = 1; off < 64; off <<= 1) s += __shfl_xor(s, off);
    __shared__ int ws4[4];
    if ((tid & 63) == 0) ws4[tid >> 6] = s;
    __syncthreads();
    if (tid == 0) blocksum[blockIdx.x] = ws4[0] + ws4[1] + ws4[2] + ws4[3];
}

// per-block exclusive scan + carry-in from blocksums
__global__ __launch_bounds__(256) void k_scan3(
    const int* __restrict__ cnt_i, const int* __restrict__ blocksum,
    int* __restrict__ base, int N)
{
    const int tid = threadIdx.x;
    const int lane = tid & 63;
    const int wv = tid >> 6;
    const int b = blockIdx.x;
    const int i0 = b * 1024 + tid * 4;

    int v[4];
#pragma unroll
    for (int k = 0; k < 4; ++k) { int i = i0 + k; v[k] = (i < N) ? cnt_i[i] : 0; }
    int tsum = v[0] + v[1] + v[2] + v[3];

    int incl = tsum;
#pragma unroll
    for (int off = 1; off < 64; off <<= 1) {
        int x = __shfl_up(incl, off);
        if (lane >= off) incl += x;
    }
    __shared__ int wsum[4];
    if (lane == 63) wsum[wv] = incl;
    __syncthreads();
    int wpre = 0;
    for (int w = 0; w < wv; ++w) wpre += wsum[w];

    int bbase = 0;
    for (int i = 0; i < b; ++i) bbase += blocksum[i];

    int excl = bbase + wpre + incl - tsum;
#pragma unroll
    for (int k = 0; k < 4; ++k) {
        int i = i0 + k;
        if (i < N) base[i] = excl;
        excl += v[k];
    }
}

__global__ __launch_bounds__(256) void k_scatter(
    const int* __restrict__ erow, const int* __restrict__ base,
    int* __restrict__ fill, int* __restrict__ perm, int E)
{
    int e = blockIdx.x * 256 + threadIdx.x;
    if (e < E) {
        int r = erow[e];
        int pos = base[r] + atomicAdd(&fill[r], 1);
        perm[pos] = e;
    }
}

// one wave per node: 16 lanes x float4 cover the 256B edge row, 4 rows in
// flight (jg = lane>>4), shfl_xor reduce, one coalesced 256B store.
__global__ __launch_bounds__(256) void k_agg(
    const float* __restrict__ edge_attr, const int* __restrict__ perm,
    const int* __restrict__ base, const int* __restrict__ cnt_i,
    float* __restrict__ agg, int N)
{
    int tid = threadIdx.x;
    int n = blockIdx.x * 4 + (tid >> 6);
    if (n >= N) return;
    int lane = tid & 63, seg = lane & 15, jg = lane >> 4;
    int s = base[n], c = cnt_i[n];
    float4 acc = make_float4(0.f, 0.f, 0.f, 0.f);
    for (int j = jg; j < c; j += 4) {
        int e = perm[s + j];
        float4 a = *reinterpret_cast<const float4*>(edge_attr + (size_t)e * EDIM + seg * 4);
        acc.x += a.x; acc.y += a.y; acc.z += a.z; acc.w += a.w;
    }
#pragma unroll
    for (int off = 16; off < 64; off <<= 1) {
        acc.x += __shfl_xor(acc.x, off);
        acc.y += __shfl_xor(acc.y, off);
        acc.z += __shfl_xor(acc.z, off);
        acc.w += __shfl_xor(acc.w, off);
    }
    if (jg == 0)
        *reinterpret_cast<float4*>(agg + (size_t)n * EDIM + seg * 4) = acc;
}

// ---------------------------------------------------------------------------
// Transpose node_w (256x128 -> 128x256) and edge_w (256x64 -> 64x256).
// ---------------------------------------------------------------------------
__global__ __launch_bounds__(256) void k_transpose(
    const float* __restrict__ node_w, const float* __restrict__ edge_w,
    float* __restrict__ node_wT, float* __restrict__ edge_wT)
{
    int idx = blockIdx.x * 256 + threadIdx.x;
    if (idx < DDIM * NDIM) {
        int k = idx / DDIM, j = idx % DDIM;
        node_wT[idx] = node_w[j * NDIM + k];
    }
    if (idx < DDIM * EDIM) {
        int k = idx / DDIM, j = idx % DDIM;
        edge_wT[idx] = edge_w[j * EDIM + k];
    }
}

// ---------------------------------------------------------------------------
// q = query @ wq.T + bq; qk[h,:] = sum_d q[h,d]*wk[h*64+d,:]; sb[h] likewise.
// ---------------------------------------------------------------------------
__global__ __launch_bounds__(256) void k_prep(
    const float* __restrict__ query, const float* __restrict__ in_w,
    const float* __restrict__ in_b, float* __restrict__ qk, float* __restrict__ sb)
{
    __shared__ float q_s[DDIM];
    __shared__ float qv[DDIM];
    int tid = threadIdx.x;
    q_s[tid] = query[tid];
    __syncthreads();
    float acc = in_b[tid];
    const float* wq = in_w + (size_t)tid * DDIM;
    for (int i = 0; i < DDIM; ++i) acc += q_s[i] * wq[i];
    qv[tid] = acc;
    __syncthreads();
    for (int h = 0; h < 4; ++h) {
        float a = 0.f;
        for (int d = 0; d < 64; ++d)
            a += qv[h * 64 + d] * in_w[(size_t)(DDIM + h * 64 + d) * DDIM + tid];
        qk[h * DDIM + tid] = a;
    }
    if (tid < 4) {
        float a = 0.f;
        for (int d = 0; d < 64; ++d) a += qv[tid * 64 + d] * in_b[DDIM + tid * 64 + d];
        sb[tid] = a;
    }
}

// ---------------------------------------------------------------------------
// Fused projection + scores (register-blocked 4x4 f32 vector GEMM).
// ---------------------------------------------------------------------------
__global__ __launch_bounds__(256) void k_proj(
    const float* __restrict__ h, const float* __restrict__ agg, const int* __restrict__ cnt_i,
    const float* __restrict__ node_wT, const float* __restrict__ edge_wT,
    const float* __restrict__ node_b, const float* __restrict__ edge_b,
    const float* __restrict__ qk, const float* __restrict__ sb,
    float* __restrict__ h_proj, float* __restrict__ scores, int N)
{
    __shared__ float h_s[TILE][NDIM + 4];
    __shared__ float a_s[TILE][EDIM + 4];
    __shared__ float qk_s[4 * DDIM];
    __shared__ float ps[64][68];
    __shared__ float ps2[4][64];
    __shared__ float cnt_s[TILE];
    __shared__ float sb_s[4];

    const int tid = threadIdx.x;
    const int n0 = blockIdx.x * TILE;

    for (int i = tid; i < 4 * DDIM; i += 256) qk_s[i] = qk[i];
    if (tid < 4) sb_s[tid] = sb[tid];
    if (tid < TILE) cnt_s[tid] = (n0 + tid < N) ? (float)cnt_i[n0 + tid] : 0.f;

    for (int i = tid; i < TILE * (NDIM / 4); i += 256) {
        int t = i / (NDIM / 4), kq = i % (NDIM / 4);
        float4 v = make_float4(0.f, 0.f, 0.f, 0.f);
        if (n0 + t < N) v = reinterpret_cast<const float4*>(h + (size_t)(n0 + t) * NDIM)[kq];
        *reinterpret_cast<float4*>(&h_s[t][kq * 4]) = v;
    }
    for (int i = tid; i < TILE * (EDIM / 4); i += 256) {
        int t = i / (EDIM / 4), kq = i % (EDIM / 4);
        float4 v = make_float4(0.f, 0.f, 0.f, 0.f);
        if (n0 + t < N) v = reinterpret_cast<const float4*>(agg + (size_t)(n0 + t) * EDIM)[kq];
        *reinterpret_cast<float4*>(&a_s[t][kq * 4]) = v;
    }
    __syncthreads();

    const int dg = tid & 63;
    const int ng = tid >> 6;
    const int j0 = dg * 4;

    float acc[4][4];
    float acc2[4][4];
#pragma unroll
    for (int t = 0; t < 4; ++t)
#pragma unroll
        for (int j = 0; j < 4; ++j) { acc[t][j] = 0.f; acc2[t][j] = 0.f; }

    for (int k0 = 0; k0 < NDIM; k0 += 4) {
        float w[4][4];
#pragma unroll
        for (int kk = 0; kk < 4; ++kk) {
            float4 wv = *reinterpret_cast<const float4*>(node_wT + (size_t)(k0 + kk) * DDIM + j0);
            w[kk][0] = wv.x; w[kk][1] = wv.y; w[kk][2] = wv.z; w[kk][3] = wv.w;
        }
#pragma unroll
        for (int t = 0; t < 4; ++t) {
            float4 hv = *reinterpret_cast<const float4*>(&h_s[ng * 4 + t][k0]);
#pragma unroll
            for (int j = 0; j < 4; ++j)
                acc[t][j] += hv.x * w[0][j] + hv.y * w[1][j] + hv.z * w[2][j] + hv.w * w[3][j];
        }
    }
    for (int k0 = 0; k0 < EDIM; k0 += 4) {
        float w[4][4];
#pragma unroll
        for (int kk = 0; kk < 4; ++kk) {
            float4 wv = *reinterpret_cast<const float4*>(edge_wT + (size_t)(k0 + kk) * DDIM + j0);
            w[kk][0] = wv.x; w[kk][1] = wv.y; w[kk][2] = wv.z; w[kk][3] = wv.w;
        }
#pragma unroll
        for (int t = 0; t < 4; ++t) {
            float4 av = *reinterpret_cast<const float4*>(&a_s[ng * 4 + t][k0]);
#pragma unroll
            for (int j = 0; j < 4; ++j)
                acc2[t][j] += av.x * w[0][j] + av.y * w[1][j] + av.z * w[2][j] + av.w * w[3][j];
        }
    }

    float4 nb4 = *reinterpret_cast<const float4*>(node_b + j0);
    float4 eb4 = *reinterpret_cast<const float4*>(edge_b + j0);
    float nb[4] = {nb4.x, nb4.y, nb4.z, nb4.w};
    float eb[4] = {eb4.x, eb4.y, eb4.z, eb4.w};

    float hp[4][4];
#pragma unroll
    for (int t = 0; t < 4; ++t) {
        float c = cnt_s[ng * 4 + t];
        float inv = 1.f / fmaxf(c, 1.f);
        float fl = (c >= 0.5f) ? 1.f : 0.f;
#pragma unroll
        for (int j = 0; j < 4; ++j)
            hp[t][j] = acc[t][j] + nb[j] + acc2[t][j] * inv + eb[j] * fl;
    }

#pragma unroll
    for (int t = 0; t < 4; ++t) {
        int n = n0 + ng * 4 + t;
        if (n < N) {
            float4 v = make_float4(hp[t][0], hp[t][1], hp[t][2], hp[t][3]);
            *reinterpret_cast<float4*>(h_proj + (size_t)n * DDIM + j0) = v;
        }
    }

    float4 qk4[4];
#pragma unroll
    for (int hh = 0; hh < 4; ++hh)
        qk4[hh] = *reinterpret_cast<const float4*>(&qk_s[hh * DDIM + j0]);
#pragma unroll
    for (int t = 0; t < 4; ++t) {
        float p[4];
#pragma unroll
        for (int hh = 0; hh < 4; ++hh) {
            float4 q4 = qk4[hh];
            p[hh] = hp[t][0] * q4.x + hp[t][1] * q4.y + hp[t][2] * q4.z + hp[t][3] * q4.w;
        }
        *reinterpret_cast<float4*>(&ps[dg][(ng * 4 + t) * 4]) =
            make_float4(p[0], p[1], p[2], p[3]);
    }
    __syncthreads();

    {
        int grp = tid >> 6;
        int th = tid & 63;
        float ssum = 0.f;
#pragma unroll
        for (int i = 0; i < 16; ++i) ssum += ps[grp * 16 + i][th];
        ps2[grp][th] = ssum;
    }
    __syncthreads();
    if (tid < 64) {
        float tot = ps2[0][tid] + ps2[1][tid] + ps2[2][tid] + ps2[3][tid];
        int t = tid >> 2, hh = tid & 3;
        int n = n0 + t;
        if (n < N) scores[(size_t)n * 4 + hh] = (tot + sb_s[hh]) * 0.125f;
    }
}

// ---------------------------------------------------------------------------
// Per-graph online-softmax pooling + output GEMM. One block per graph.
// ---------------------------------------------------------------------------
__global__ __launch_bounds__(256) void k_pool(
    const float* __restrict__ h_proj, const float* __restrict__ scores,
    const int* __restrict__ batch, const float* __restrict__ in_w,
    const float* __restrict__ in_b, const float* __restrict__ out_w,
    const float* __restrict__ out_b, float* __restrict__ out, int N)
{
    __shared__ float sc_s[256 * 4];
    __shared__ float red_s[16];
    __shared__ float hb_s[4 * DDIM];

    const int g = blockIdx.x;
    const int tid = threadIdx.x;
    const int lane = tid & 63;
    const int wave = tid >> 6;

    int lo = 0, hi = N;
    while (lo < hi) { int mid = (lo + hi) >> 1; if (batch[mid] < g) lo = mid + 1; else hi = mid; }
    const int s = lo;
    hi = N;
    while (lo < hi) { int mid = (lo + hi) >> 1; if (batch[mid] < g + 1) lo = mid + 1; else hi = mid; }
    const int e = lo;

    float m[4], dn[4], hb[4];
#pragma unroll
    for (int hh = 0; hh < 4; ++hh) { m[hh] = -INFINITY; dn[hh] = 0.f; hb[hh] = 0.f; }

    const int h = tid & 3;

    for (int c = s; c < e; c += 256) {
        int cn = min(256, e - c);
        __syncthreads();
        if (tid < cn)
            *reinterpret_cast<float4*>(&sc_s[tid * 4]) =
                *reinterpret_cast<const float4*>(scores + (size_t)(c + tid) * 4);
        __syncthreads();

        float lm = -INFINITY;
        for (int n = tid >> 2; n < cn; n += 64) lm = fmaxf(lm, sc_s[n * 4 + h]);
#pragma unroll
        for (int off = 4; off < 64; off <<= 1) lm = fmaxf(lm, __shfl_xor(lm, off));
        if (lane < 4) red_s[wave * 4 + lane] = lm;
        __syncthreads();

        float nm[4];
#pragma unroll
        for (int hh = 0; hh < 4; ++hh) {
            float cm = fmaxf(fmaxf(red_s[hh], red_s[4 + hh]),
                             fmaxf(red_s[8 + hh], red_s[12 + hh]));
            nm[hh] = fmaxf(m[hh], cm);
            float sc = expf(m[hh] - nm[hh]);
            dn[hh] *= sc; hb[hh] *= sc; m[hh] = nm[hh];
        }
        __syncthreads();

        float mh = (h == 0) ? nm[0] : (h == 1) ? nm[1] : (h == 2) ? nm[2] : nm[3];
        float ld = 0.f;
        for (int idx = tid; idx < cn * 4; idx += 256) {
            float w = expf(sc_s[idx] - mh);
            sc_s[idx] = w;
            ld += w;
        }
#pragma unroll
        for (int off = 4; off < 64; off <<= 1) ld += __shfl_xor(ld, off);
        __syncthreads();
        if (lane < 4) red_s[wave * 4 + lane] = ld;
        __syncthreads();
#pragma unroll
        for (int hh = 0; hh < 4; ++hh)
            dn[hh] += red_s[hh] + red_s[4 + hh] + red_s[8 + hh] + red_s[12 + hh];

#pragma unroll 4
        for (int n = 0; n < cn; ++n) {
            float val = h_proj[(size_t)(c + n) * DDIM + tid];
            float4 w4 = *reinterpret_cast<const float4*>(&sc_s[n * 4]);
            hb[0] += w4.x * val;
            hb[1] += w4.y * val;
            hb[2] += w4.z * val;
            hb[3] += w4.w * val;
        }
    }

    __syncthreads();
    const float has = (e > s) ? 1.f : 0.f;
#pragma unroll
    for (int hh = 0; hh < 4; ++hh)
        hb_s[hh * DDIM + tid] = hb[hh] / fmaxf(dn[hh], 1e-30f);
    __syncthreads();

    const int jh = tid >> 6;
    const float* wv_row = in_w + (size_t)(2 * DDIM + tid) * DDIM;
    const float* hbr = &hb_s[jh * DDIM];
    float p = 0.f;
    for (int i = 0; i < DDIM; i += 4) {
        float4 a = *reinterpret_cast<const float4*>(hbr + i);
        float4 b = *reinterpret_cast<const float4*>(wv_row + i);
        p += a.x * b.x + a.y * b.y + a.z * b.z + a.w * b.w;
    }
    p = (p + in_b[2 * DDIM + tid]) * has;
    sc_s[tid] = p;
    __syncthreads();

    const float* ow_row = out_w + (size_t)tid * DDIM;
    float o = out_b[tid];
    for (int i = 0; i < DDIM; i += 4) {
        float4 a = *reinterpret_cast<const float4*>(&sc_s[i]);
        float4 b = *reinterpret_cast<const float4*>(ow_row + i);
        o += a.x * b.x + a.y * b.y + a.z * b.z + a.w * b.w;
    }
    out[(size_t)g * DDIM + tid] = o;
}

// ---------------------------------------------------------------------------
extern "C" void kernel_launch(void* const* d_in, const int* in_sizes, int n_in,
                              void* d_out, int out_size, void* d_ws, size_t ws_size,
                              hipStream_t stream) {
    const float* h         = (const float*)d_in[0];
    const int*   edge_idx  = (const int*)d_in[1];
    const float* edge_attr = (const float*)d_in[2];
    const int*   batch     = (const int*)d_in[3];
    const float* node_w    = (const float*)d_in[5];
    const float* node_b    = (const float*)d_in[6];
    const float* edge_w    = (const float*)d_in[7];
    const float* edge_b    = (const float*)d_in[8];
    const float* query     = (const float*)d_in[9];
    const float* in_w      = (const float*)d_in[10];
    const float* in_b      = (const float*)d_in[11];
    const float* out_w     = (const float*)d_in[12];
    const float* out_b     = (const float*)d_in[13];
    float* out = (float*)d_out;

    const int N = in_sizes[0] / NDIM;
    const int E = in_sizes[2] / EDIM;
    const int G = out_size / DDIM;
    const int nblk1 = (N + 1023) / 1024;

    char* ws = (char*)d_ws;
    size_t off = 0;
    auto alloc = [&](size_t bytes) { void* p = ws + off; off += (bytes + 255) & ~(size_t)255; return p; };

    int*   cnt_i    = (int*)alloc((size_t)N * 4 * 2);   // cnt_i + fill adjacent (one memset)
    int*   fill     = cnt_i + N;
    int*   base     = (int*)alloc((size_t)N * 4);
    int*   perm     = (int*)alloc((size_t)E * 4);
    int*   blocksum = (int*)alloc((size_t)nblk1 * 4);
    float* agg      = (float*)alloc((size_t)N * EDIM * 4);
    float* h_proj   = (float*)alloc((size_t)N * DDIM * 4);
    float* scores   = (float*)alloc((size_t)N * 4 * 4);
    float* node_wT  = (float*)alloc((size_t)DDIM * NDIM * 4);
    float* edge_wT  = (float*)alloc((size_t)DDIM * EDIM * 4);
    float* qk       = (float*)alloc(4 * DDIM * 4);
    float* sb       = (float*)alloc(16 * 4);

    hipMemsetAsync(cnt_i, 0, (size_t)N * 2 * sizeof(int), stream);

    k_hist<<<(E + 255) / 256, 256, 0, stream>>>(edge_idx, cnt_i, E);
    k_scan1<<<nblk1, 256, 0, stream>>>(cnt_i, blocksum, N);
    k_scan3<<<nblk1, 256, 0, stream>>>(cnt_i, blocksum, base, N);
    k_scatter<<<(E + 255) / 256, 256, 0, stream>>>(edge_idx, base, fill, perm, E);
    k_agg<<<(N + 3) / 4, 256, 0, stream>>>(edge_attr, perm, base, cnt_i, agg, N);

    k_transpose<<<(DDIM * NDIM + 255) / 256, 256, 0, stream>>>(node_w, edge_w, node_wT, edge_wT);
    k_prep<<<1, 256, 0, stream>>>(query, in_w, in_b, qk, sb);
    k_proj<<<(N + TILE - 1) / TILE, 256, 0, stream>>>(
        h, agg, cnt_i, node_wT, edge_wT, node_b, edge_b, qk, sb, h_proj, scores, N);
    k_pool<<<G, 256, 0, stream>>>(h_proj, scores, batch, in_w, in_b, out_w, out_b, out, N);
}

// Round 3
// 269.565 us; speedup vs baseline: 3.7017x; 1.5410x over previous
//
#include <hip/hip_runtime.h>
#include <hip/hip_bf16.h>
#include <math.h>

#define NDIM 128
#define EDIM 64
#define DDIM 256
#define KTOT 192          // 128 node + 64 edge
#define BM 32             // nodes per k_proj block
#define APK_STRIDE 204    // u32 stride for A_pk rows (bank-friendly, 16B aligned)
#define HPB_STRIDE 264    // ushort stride for hpbuf rows

typedef __attribute__((ext_vector_type(8))) short short8;
typedef __attribute__((ext_vector_type(4))) float floatx4;

__device__ inline ushort f2bf(float x) {
    uint32_t u = __float_as_uint(x);
    uint32_t r = (u + 0x7fff + ((u >> 16) & 1)) >> 16;
    return (ushort)r;
}
__device__ inline float bf2f(ushort h) { return __uint_as_float(((uint32_t)h) << 16); }
__device__ inline uint32_t pack_hilo(float x) {
    ushort hi = f2bf(x);
    ushort lo = f2bf(x - bf2f(hi));
    return (uint32_t)hi | ((uint32_t)lo << 16);
}

// ---------------------------------------------------------------------------
// Edge binning pipeline: hist -> scan -> scatter(perm) -> segmented reduce
// ---------------------------------------------------------------------------
__global__ __launch_bounds__(256) void k_hist(
    const int* __restrict__ erow, int* __restrict__ cnt_i, int E)
{
    int e = blockIdx.x * 256 + threadIdx.x;
    if (e < E) atomicAdd(&cnt_i[erow[e]], 1);
}

__global__ __launch_bounds__(256) void k_scan1(
    const int* __restrict__ cnt_i, int* __restrict__ blocksum, int N)
{
    int tid = threadIdx.x;
    int i0 = blockIdx.x * 1024 + tid * 4;
    int s = 0;
#pragma unroll
    for (int k = 0; k < 4; ++k) { int i = i0 + k; if (i < N) s += cnt_i[i]; }
#pragma unroll
    for (int off = 1; off < 64; off <<= 1) s += __shfl_xor(s, off);
    __shared__ int ws4[4];
    if ((tid & 63) == 0) ws4[tid >> 6] = s;
    __syncthreads();
    if (tid == 0) blocksum[blockIdx.x] = ws4[0] + ws4[1] + ws4[2] + ws4[3];
}

__global__ __launch_bounds__(256) void k_scan3(
    const int* __restrict__ cnt_i, const int* __restrict__ blocksum,
    int* __restrict__ base, int N)
{
    const int tid = threadIdx.x;
    const int lane = tid & 63;
    const int wv = tid >> 6;
    const int b = blockIdx.x;
    const int i0 = b * 1024 + tid * 4;

    int v[4];
#pragma unroll
    for (int k = 0; k < 4; ++k) { int i = i0 + k; v[k] = (i < N) ? cnt_i[i] : 0; }
    int tsum = v[0] + v[1] + v[2] + v[3];

    int incl = tsum;
#pragma unroll
    for (int off = 1; off < 64; off <<= 1) {
        int x = __shfl_up(incl, off);
        if (lane >= off) incl += x;
    }
    __shared__ int wsum[4];
    if (lane == 63) wsum[wv] = incl;
    __syncthreads();
    int wpre = 0;
    for (int w = 0; w < wv; ++w) wpre += wsum[w];

    int bbase = 0;
    for (int i = 0; i < b; ++i) bbase += blocksum[i];

    int excl = bbase + wpre + incl - tsum;
#pragma unroll
    for (int k = 0; k < 4; ++k) {
        int i = i0 + k;
        if (i < N) base[i] = excl;
        excl += v[k];
    }
}

__global__ __launch_bounds__(256) void k_scatter(
    const int* __restrict__ erow, const int* __restrict__ base,
    int* __restrict__ fill, int* __restrict__ perm, int E)
{
    int e = blockIdx.x * 256 + threadIdx.x;
    if (e < E) {
        int r = erow[e];
        int pos = base[r] + atomicAdd(&fill[r], 1);
        perm[pos] = e;
    }
}

__global__ __launch_bounds__(256) void k_agg(
    const float* __restrict__ edge_attr, const int* __restrict__ perm,
    const int* __restrict__ base, const int* __restrict__ cnt_i,
    float* __restrict__ agg, int N)
{
    int tid = threadIdx.x;
    int n = blockIdx.x * 4 + (tid >> 6);
    if (n >= N) return;
    int lane = tid & 63, seg = lane & 15, jg = lane >> 4;
    int s = base[n], c = cnt_i[n];
    float4 acc = make_float4(0.f, 0.f, 0.f, 0.f);
    for (int j = jg; j < c; j += 4) {
        int e = perm[s + j];
        float4 a = *reinterpret_cast<const float4*>(edge_attr + (size_t)e * EDIM + seg * 4);
        acc.x += a.x; acc.y += a.y; acc.z += a.z; acc.w += a.w;
    }
#pragma unroll
    for (int off = 16; off < 64; off <<= 1) {
        acc.x += __shfl_xor(acc.x, off);
        acc.y += __shfl_xor(acc.y, off);
        acc.z += __shfl_xor(acc.z, off);
        acc.w += __shfl_xor(acc.w, off);
    }
    if (jg == 0)
        *reinterpret_cast<float4*>(agg + (size_t)n * EDIM + seg * 4) = acc;
}

// ---------------------------------------------------------------------------
// Pre-swizzle combined weights [K=192][256] into MFMA B-fragment order,
// split hi/lo bf16. Layout: whi[((c*6+s)*64+l)*8 + i], k=s*32+(l>>4)*8+i,
// col=c*16+(l&15).
// ---------------------------------------------------------------------------
__global__ __launch_bounds__(256) void k_prepw(
    const float* __restrict__ node_w, const float* __restrict__ edge_w,
    ushort* __restrict__ whi, ushort* __restrict__ wlo)
{
    int idx = blockIdx.x * 256 + threadIdx.x;
    if (idx >= 16 * 6 * 64 * 8) return;
    int i = idx & 7;
    int l = (idx >> 3) & 63;
    int t2 = idx >> 9;
    int s = t2 % 6;
    int c = t2 / 6;
    int k = s * 32 + (l >> 4) * 8 + i;
    int col = c * 16 + (l & 15);
    float val = (k < NDIM) ? node_w[(size_t)col * NDIM + k]
                           : edge_w[(size_t)col * EDIM + (k - NDIM)];
    ushort hi = f2bf(val);
    ushort lo = f2bf(val - bf2f(hi));
    whi[idx] = hi;
    wlo[idx] = lo;
}

// ---------------------------------------------------------------------------
// q = query @ wq.T + bq; qk[h,:] = sum_d q[h,d]*wk[h*64+d,:]; sb[h] likewise.
// ---------------------------------------------------------------------------
__global__ __launch_bounds__(256) void k_prep(
    const float* __restrict__ query, const float* __restrict__ in_w,
    const float* __restrict__ in_b, float* __restrict__ qk, float* __restrict__ sb)
{
    __shared__ float q_s[DDIM];
    __shared__ float qv[DDIM];
    int tid = threadIdx.x;
    q_s[tid] = query[tid];
    __syncthreads();
    float acc = in_b[tid];
    const float* wq = in_w + (size_t)tid * DDIM;
    for (int i = 0; i < DDIM; ++i) acc += q_s[i] * wq[i];
    qv[tid] = acc;
    __syncthreads();
    for (int h = 0; h < 4; ++h) {
        float a = 0.f;
        for (int d = 0; d < 64; ++d)
            a += qv[h * 64 + d] * in_w[(size_t)(DDIM + h * 64 + d) * DDIM + tid];
        qk[h * DDIM + tid] = a;
    }
    if (tid < 4) {
        float a = 0.f;
        for (int d = 0; d < 64; ++d) a += qv[tid * 64 + d] * in_b[DDIM + tid * 64 + d];
        sb[tid] = a;
    }
}

// ---------------------------------------------------------------------------
// MFMA projection + scores. 32 nodes/block, K=192, 256 outputs.
// Split-precision: acc = ahi*bhi + ahi*blo + alo*bhi  (~f32 accuracy).
// Wave w: rb=w&1 (16-row strip), cb=w>>1 (128-col block), 8 col-tiles.
// Epilogue: + node_b + fl*edge_b, score partials vs qk, bf16 h_proj store.
// ---------------------------------------------------------------------------
__global__ __launch_bounds__(256) void k_proj_mfma(
    const float* __restrict__ h, const float* __restrict__ agg, const int* __restrict__ cnt_i,
    const ushort* __restrict__ whi, const ushort* __restrict__ wlo,
    const float* __restrict__ node_b, const float* __restrict__ edge_b,
    const float* __restrict__ qk, const float* __restrict__ sb,
    ushort* __restrict__ h_proj_bf, float* __restrict__ scores, int N)
{
    extern __shared__ char smem[];
    uint32_t* A_pk = (uint32_t*)smem;            // [BM][APK_STRIDE]
    ushort*   hpbuf = (ushort*)smem;             // [BM][HPB_STRIDE] (aliased after K-loop)
    __shared__ float ps_s[2][BM][4];
    __shared__ float cnt_s[BM];

    const int tid = threadIdx.x;
    const int n0 = blockIdx.x * BM;

    if (tid < BM) {
        int n = n0 + tid;
        cnt_s[tid] = (n < N) ? (float)cnt_i[n] : 0.f;
    }
    __syncthreads();

    // stage h (32 x 128 f32 -> packed hi/lo)
    const float4* h4 = reinterpret_cast<const float4*>(h);
#pragma unroll
    for (int it = 0; it < 4; ++it) {
        int idx4 = tid + 256 * it;          // 0..1023
        int node = idx4 >> 5;               // /32 float4 per row
        int kq = idx4 & 31;
        float4 v = make_float4(0.f, 0.f, 0.f, 0.f);
        if (n0 + node < N) v = h4[(size_t)(n0 + node) * 32 + kq];
        uint32_t* dst = &A_pk[node * APK_STRIDE + kq * 4];
        dst[0] = pack_hilo(v.x); dst[1] = pack_hilo(v.y);
        dst[2] = pack_hilo(v.z); dst[3] = pack_hilo(v.w);
    }
    // stage agg/cnt (32 x 64)
    const float4* a4 = reinterpret_cast<const float4*>(agg);
#pragma unroll
    for (int it = 0; it < 2; ++it) {
        int idx4 = tid + 256 * it;          // 0..511
        int node = idx4 >> 4;               // /16 float4 per row
        int kq = idx4 & 15;
        float4 v = make_float4(0.f, 0.f, 0.f, 0.f);
        if (n0 + node < N) v = a4[(size_t)(n0 + node) * 16 + kq];
        float inv = 1.f / fmaxf(cnt_s[node], 1.f);
        uint32_t* dst = &A_pk[node * APK_STRIDE + NDIM + kq * 4];
        dst[0] = pack_hilo(v.x * inv); dst[1] = pack_hilo(v.y * inv);
        dst[2] = pack_hilo(v.z * inv); dst[3] = pack_hilo(v.w * inv);
    }
    __syncthreads();

    const int lane = tid & 63;
    const int w = tid >> 6;
    const int rb = w & 1;
    const int cb = w >> 1;
    const int arow = rb * 16 + (lane & 15);
    const uint32_t* arow_p = &A_pk[arow * APK_STRIDE + (lane >> 4) * 8];

    floatx4 acc[8];
#pragma unroll
    for (int t = 0; t < 8; ++t) acc[t] = 0.f;

#pragma unroll 2
    for (int s = 0; s < 6; ++s) {
        uint32_t au[8];
#pragma unroll
        for (int j = 0; j < 8; ++j) au[j] = arow_p[s * 32 + j];
        short8 ahi, alo;
#pragma unroll
        for (int j = 0; j < 8; ++j) {
            ahi[j] = (short)(au[j] & 0xffffu);
            alo[j] = (short)(au[j] >> 16);
        }
#pragma unroll
        for (int t = 0; t < 8; ++t) {
            size_t boff = ((size_t)((cb * 8 + t) * 6 + s) * 64 + lane) * 8;
            short8 bhi = *reinterpret_cast<const short8*>(whi + boff);
            short8 blo = *reinterpret_cast<const short8*>(wlo + boff);
            acc[t] = __builtin_amdgcn_mfma_f32_16x16x32_bf16(ahi, bhi, acc[t], 0, 0, 0);
            acc[t] = __builtin_amdgcn_mfma_f32_16x16x32_bf16(ahi, blo, acc[t], 0, 0, 0);
            acc[t] = __builtin_amdgcn_mfma_f32_16x16x32_bf16(alo, bhi, acc[t], 0, 0, 0);
        }
    }
    __syncthreads();   // all waves done reading A_pk; hpbuf may now alias it

    // epilogue constants
    float nb_l[8], eb_l[8];
    float qk_l[4][8];
#pragma unroll
    for (int t = 0; t < 8; ++t) {
        int col = cb * 128 + t * 16 + (lane & 15);
        nb_l[t] = node_b[col];
        eb_l[t] = edge_b[col];
#pragma unroll
        for (int hh = 0; hh < 4; ++hh) qk_l[hh][t] = qk[hh * DDIM + col];
    }
    const int rbase = rb * 16 + (lane >> 4) * 4;
    float fl[4];
#pragma unroll
    for (int r = 0; r < 4; ++r) fl[r] = (cnt_s[rbase + r] >= 0.5f) ? 1.f : 0.f;

    float ph[4][4];
#pragma unroll
    for (int r = 0; r < 4; ++r)
#pragma unroll
        for (int hh = 0; hh < 4; ++hh) ph[r][hh] = 0.f;

#pragma unroll
    for (int t = 0; t < 8; ++t) {
#pragma unroll
        for (int r = 0; r < 4; ++r) {
            float hp = acc[t][r] + nb_l[t] + fl[r] * eb_l[t];
#pragma unroll
            for (int hh = 0; hh < 4; ++hh) ph[r][hh] += hp * qk_l[hh][t];
            hpbuf[(rbase + r) * HPB_STRIDE + cb * 128 + t * 16 + (lane & 15)] = f2bf(hp);
        }
    }

    // reduce score partials across the 16 lanes of each group
#pragma unroll
    for (int r = 0; r < 4; ++r)
#pragma unroll
        for (int hh = 0; hh < 4; ++hh) {
            float v = ph[r][hh];
            v += __shfl_xor(v, 1); v += __shfl_xor(v, 2);
            v += __shfl_xor(v, 4); v += __shfl_xor(v, 8);
            ph[r][hh] = v;
        }
    if ((lane & 15) == 0) {
#pragma unroll
        for (int r = 0; r < 4; ++r)
#pragma unroll
            for (int hh = 0; hh < 4; ++hh)
                ps_s[cb][rbase + r][hh] = ph[r][hh];
    }
    __syncthreads();

    // final score write
    if (tid < 128) {
        int row = tid >> 2, hh = tid & 3;
        int n = n0 + row;
        if (n < N)
            scores[(size_t)n * 4 + hh] =
                (ps_s[0][row][hh] + ps_s[1][row][hh] + sb[hh]) * 0.125f;
    }

    // coalesced bf16 h_proj store: 8 threads per row x 32 ushort
    {
        int row = tid >> 3, seg = tid & 7;
        int n = n0 + row;
        if (n < N) {
#pragma unroll
            for (int q = 0; q < 4; ++q) {
                short8 v = *reinterpret_cast<const short8*>(
                    &hpbuf[row * HPB_STRIDE + seg * 32 + q * 8]);
                *reinterpret_cast<short8*>(
                    &h_proj_bf[(size_t)n * DDIM + seg * 32 + q * 8]) = v;
            }
        }
    }
}

// ---------------------------------------------------------------------------
// Half-graph online-softmax pooling partials. Block b: graph b>>1, half b&1.
// Writes m[4], denom[4], hbar-unnormalized [4][256] per block.
// ---------------------------------------------------------------------------
__global__ __launch_bounds__(256) void k_pool2(
    const ushort* __restrict__ h_proj_bf, const float* __restrict__ scores,
    const int* __restrict__ batch,
    float* __restrict__ pm, float* __restrict__ pd, float* __restrict__ phb, int N)
{
    __shared__ float sc_s[256 * 4];
    __shared__ float red_s[16];

    const int b = blockIdx.x;
    const int g = b >> 1;
    const int half = b & 1;
    const int tid = threadIdx.x;
    const int lane = tid & 63;
    const int wave = tid >> 6;

    int lo = 0, hi = N;
    while (lo < hi) { int mid = (lo + hi) >> 1; if (batch[mid] < g) lo = mid + 1; else hi = mid; }
    const int s = lo;
    hi = N;
    while (lo < hi) { int mid = (lo + hi) >> 1; if (batch[mid] < g + 1) lo = mid + 1; else hi = mid; }
    const int e = lo;
    const int mid = s + ((e - s + 1) >> 1);
    const int cs = half ? mid : s;
    const int ce = half ? e : mid;

    float m[4], dn[4], hb[4];
#pragma unroll
    for (int hh = 0; hh < 4; ++hh) { m[hh] = -INFINITY; dn[hh] = 0.f; hb[hh] = 0.f; }

    const int h = tid & 3;

    for (int c = cs; c < ce; c += 256) {
        int cn = min(256, ce - c);
        __syncthreads();
        if (tid < cn)
            *reinterpret_cast<float4*>(&sc_s[tid * 4]) =
                *reinterpret_cast<const float4*>(scores + (size_t)(c + tid) * 4);
        __syncthreads();

        float lm = -INFINITY;
        for (int n = tid >> 2; n < cn; n += 64) lm = fmaxf(lm, sc_s[n * 4 + h]);
#pragma unroll
        for (int off = 4; off < 64; off <<= 1) lm = fmaxf(lm, __shfl_xor(lm, off));
        if (lane < 4) red_s[wave * 4 + lane] = lm;
        __syncthreads();

        float nm[4];
#pragma unroll
        for (int hh = 0; hh < 4; ++hh) {
            float cm = fmaxf(fmaxf(red_s[hh], red_s[4 + hh]),
                             fmaxf(red_s[8 + hh], red_s[12 + hh]));
            nm[hh] = fmaxf(m[hh], cm);
            float sc = expf(m[hh] - nm[hh]);
            dn[hh] *= sc; hb[hh] *= sc; m[hh] = nm[hh];
        }
        __syncthreads();

        float mh = (h == 0) ? nm[0] : (h == 1) ? nm[1] : (h == 2) ? nm[2] : nm[3];
        float ld = 0.f;
        for (int idx = tid; idx < cn * 4; idx += 256) {
            float wv = expf(sc_s[idx] - mh);
            sc_s[idx] = wv;
            ld += wv;
        }
#pragma unroll
        for (int off = 4; off < 64; off <<= 1) ld += __shfl_xor(ld, off);
        __syncthreads();
        if (lane < 4) red_s[wave * 4 + lane] = ld;
        __syncthreads();
#pragma unroll
        for (int hh = 0; hh < 4; ++hh)
            dn[hh] += red_s[hh] + red_s[4 + hh] + red_s[8 + hh] + red_s[12 + hh];

#pragma unroll 4
        for (int n = 0; n < cn; ++n) {
            float val = bf2f(h_proj_bf[(size_t)(c + n) * DDIM + tid]);
            float4 w4 = *reinterpret_cast<const float4*>(&sc_s[n * 4]);
            hb[0] += w4.x * val;
            hb[1] += w4.y * val;
            hb[2] += w4.z * val;
            hb[3] += w4.w * val;
        }
    }

    if (tid < 4) { pm[b * 4 + tid] = m[tid]; pd[b * 4 + tid] = dn[tid]; }
#pragma unroll
    for (int hh = 0; hh < 4; ++hh)
        phb[(size_t)(b * 4 + hh) * DDIM + tid] = hb[hh];
}

// ---------------------------------------------------------------------------
// Merge two halves + value/output GEMMs. One block per graph.
// ---------------------------------------------------------------------------
__global__ __launch_bounds__(256) void k_out(
    const float* __restrict__ pm, const float* __restrict__ pd, const float* __restrict__ phb,
    const float* __restrict__ in_w, const float* __restrict__ in_b,
    const float* __restrict__ out_w, const float* __restrict__ out_b,
    float* __restrict__ out)
{
    __shared__ float hb_s[4 * DDIM];
    __shared__ float po_s[DDIM];

    const int g = blockIdx.x;
    const int tid = threadIdx.x;
    const int b0 = 2 * g, b1 = 2 * g + 1;

    float dnm[4], sc0[4], sc1[4];
    float M0 = -INFINITY;
#pragma unroll
    for (int hh = 0; hh < 4; ++hh) {
        float m0 = pm[b0 * 4 + hh], m1 = pm[b1 * 4 + hh];
        float Mh = fmaxf(m0, m1);
        sc0[hh] = (m0 == -INFINITY) ? 0.f : expf(m0 - Mh);
        sc1[hh] = (m1 == -INFINITY) ? 0.f : expf(m1 - Mh);
        dnm[hh] = pd[b0 * 4 + hh] * sc0[hh] + pd[b1 * 4 + hh] * sc1[hh];
        if (hh == 0) M0 = Mh;
    }
    const float has = (M0 > -INFINITY) ? 1.f : 0.f;

#pragma unroll
    for (int hh = 0; hh < 4; ++hh) {
        float hb = phb[(size_t)(b0 * 4 + hh) * DDIM + tid] * sc0[hh]
                 + phb[(size_t)(b1 * 4 + hh) * DDIM + tid] * sc1[hh];
        hb_s[hh * DDIM + tid] = hb / fmaxf(dnm[hh], 1e-30f);
    }
    __syncthreads();

    const int jh = tid >> 6;
    const float* wv_row = in_w + (size_t)(2 * DDIM + tid) * DDIM;
    const float* hbr = &hb_s[jh * DDIM];
    float p = 0.f;
    for (int i = 0; i < DDIM; i += 4) {
        float4 a = *reinterpret_cast<const float4*>(hbr + i);
        float4 bb = *reinterpret_cast<const float4*>(wv_row + i);
        p += a.x * bb.x + a.y * bb.y + a.z * bb.z + a.w * bb.w;
    }
    p = (p + in_b[2 * DDIM + tid]) * has;
    po_s[tid] = p;
    __syncthreads();

    const float* ow_row = out_w + (size_t)tid * DDIM;
    float o = out_b[tid];
    for (int i = 0; i < DDIM; i += 4) {
        float4 a = *reinterpret_cast<const float4*>(&po_s[i]);
        float4 bb = *reinterpret_cast<const float4*>(ow_row + i);
        o += a.x * bb.x + a.y * bb.y + a.z * bb.z + a.w * bb.w;
    }
    out[(size_t)g * DDIM + tid] = o;
}

// ---------------------------------------------------------------------------
extern "C" void kernel_launch(void* const* d_in, const int* in_sizes, int n_in,
                              void* d_out, int out_size, void* d_ws, size_t ws_size,
                              hipStream_t stream) {
    const float* h         = (const float*)d_in[0];
    const int*   edge_idx  = (const int*)d_in[1];
    const float* edge_attr = (const float*)d_in[2];
    const int*   batch     = (const int*)d_in[3];
    const float* node_w    = (const float*)d_in[5];
    const float* node_b    = (const float*)d_in[6];
    const float* edge_w    = (const float*)d_in[7];
    const float* edge_b    = (const float*)d_in[8];
    const float* query     = (const float*)d_in[9];
    const float* in_w      = (const float*)d_in[10];
    const float* in_b      = (const float*)d_in[11];
    const float* out_w     = (const float*)d_in[12];
    const float* out_b     = (const float*)d_in[13];
    float* out = (float*)d_out;

    const int N = in_sizes[0] / NDIM;
    const int E = in_sizes[2] / EDIM;
    const int G = out_size / DDIM;
    const int nblk1 = (N + 1023) / 1024;
    const int NSWZ = 16 * 6 * 64 * 8;   // 49152

    char* ws = (char*)d_ws;
    size_t off = 0;
    auto alloc = [&](size_t bytes) { void* p = ws + off; off += (bytes + 255) & ~(size_t)255; return p; };

    int*    cnt_i      = (int*)alloc((size_t)N * 4 * 2);
    int*    fill       = cnt_i + N;
    int*    base       = (int*)alloc((size_t)N * 4);
    int*    perm       = (int*)alloc((size_t)E * 4);
    int*    blocksum   = (int*)alloc((size_t)nblk1 * 4);
    float*  agg        = (float*)alloc((size_t)N * EDIM * 4);
    ushort* h_proj_bf  = (ushort*)alloc((size_t)N * DDIM * 2);
    float*  scores     = (float*)alloc((size_t)N * 4 * 4);
    ushort* whi        = (ushort*)alloc((size_t)NSWZ * 2);
    ushort* wlo        = (ushort*)alloc((size_t)NSWZ * 2);
    float*  qk         = (float*)alloc(4 * DDIM * 4);
    float*  sb         = (float*)alloc(16 * 4);
    float*  pm         = (float*)alloc((size_t)2 * G * 4 * 4);
    float*  pd         = (float*)alloc((size_t)2 * G * 4 * 4);
    float*  phb        = (float*)alloc((size_t)2 * G * 4 * DDIM * 4);

    hipMemsetAsync(cnt_i, 0, (size_t)N * 2 * sizeof(int), stream);

    k_hist<<<(E + 255) / 256, 256, 0, stream>>>(edge_idx, cnt_i, E);
    k_scan1<<<nblk1, 256, 0, stream>>>(cnt_i, blocksum, N);
    k_scan3<<<nblk1, 256, 0, stream>>>(cnt_i, blocksum, base, N);
    k_scatter<<<(E + 255) / 256, 256, 0, stream>>>(edge_idx, base, fill, perm, E);
    k_agg<<<(N + 3) / 4, 256, 0, stream>>>(edge_attr, perm, base, cnt_i, agg, N);

    k_prepw<<<(NSWZ + 255) / 256, 256, 0, stream>>>(node_w, edge_w, whi, wlo);
    k_prep<<<1, 256, 0, stream>>>(query, in_w, in_b, qk, sb);

    const int ldsA = BM * APK_STRIDE * 4;   // 26112 B dynamic LDS
    k_proj_mfma<<<(N + BM - 1) / BM, 256, ldsA, stream>>>(
        h, agg, cnt_i, whi, wlo, node_b, edge_b, qk, sb, h_proj_bf, scores, N);

    k_pool2<<<2 * G, 256, 0, stream>>>(h_proj_bf, scores, batch, pm, pd, phb, N);
    k_out<<<G, 256, 0, stream>>>(pm, pd, phb, in_w, in_b, out_w, out_b, out);
}

// Round 4
// 253.376 us; speedup vs baseline: 3.9382x; 1.0639x over previous
//
#include <hip/hip_runtime.h>
#include <hip/hip_bf16.h>
#include <math.h>

#define NDIM 128
#define EDIM 64
#define DDIM 256
#define KTOT 192          // 128 node + 64 edge
#define BM 32             // nodes per k_proj block
#define APK_STRIDE 204    // u32 stride for A_pk rows (bank-friendly, 16B aligned)
#define HPB_STRIDE 264    // ushort stride for hpbuf rows
#define NSPLIT 4          // pool partials per graph

typedef __attribute__((ext_vector_type(8))) short short8;
typedef __attribute__((ext_vector_type(4))) float floatx4;

__device__ inline ushort f2bf(float x) {
    uint32_t u = __float_as_uint(x);
    uint32_t r = (u + 0x7fff + ((u >> 16) & 1)) >> 16;
    return (ushort)r;
}
__device__ inline float bf2f(ushort h) { return __uint_as_float(((uint32_t)h) << 16); }
__device__ inline uint32_t pack_hilo(float x) {
    ushort hi = f2bf(x);
    ushort lo = f2bf(x - bf2f(hi));
    return (uint32_t)hi | ((uint32_t)lo << 16);
}

// ---------------------------------------------------------------------------
// Zero-fill (replaces pathologically slow in-graph rocclr fillBuffer node)
// ---------------------------------------------------------------------------
__global__ __launch_bounds__(256) void k_zero(int* __restrict__ p, int n)
{
    int i = blockIdx.x * 256 + threadIdx.x;
    if (i < n) p[i] = 0;
}

// ---------------------------------------------------------------------------
// Edge binning pipeline: hist -> scan -> scatter(perm) -> segmented reduce
// ---------------------------------------------------------------------------
__global__ __launch_bounds__(256) void k_hist(
    const int* __restrict__ erow, int* __restrict__ cnt_i, int E)
{
    int e = blockIdx.x * 256 + threadIdx.x;
    if (e < E) atomicAdd(&cnt_i[erow[e]], 1);
}

__global__ __launch_bounds__(256) void k_scan1(
    const int* __restrict__ cnt_i, int* __restrict__ blocksum, int N)
{
    int tid = threadIdx.x;
    int i0 = blockIdx.x * 1024 + tid * 4;
    int s = 0;
#pragma unroll
    for (int k = 0; k < 4; ++k) { int i = i0 + k; if (i < N) s += cnt_i[i]; }
#pragma unroll
    for (int off = 1; off < 64; off <<= 1) s += __shfl_xor(s, off);
    __shared__ int ws4[4];
    if ((tid & 63) == 0) ws4[tid >> 6] = s;
    __syncthreads();
    if (tid == 0) blocksum[blockIdx.x] = ws4[0] + ws4[1] + ws4[2] + ws4[3];
}

__global__ __launch_bounds__(256) void k_scan3(
    const int* __restrict__ cnt_i, const int* __restrict__ blocksum,
    int* __restrict__ base, int N)
{
    const int tid = threadIdx.x;
    const int lane = tid & 63;
    const int wv = tid >> 6;
    const int b = blockIdx.x;
    const int i0 = b * 1024 + tid * 4;

    int v[4];
#pragma unroll
    for (int k = 0; k < 4; ++k) { int i = i0 + k; v[k] = (i < N) ? cnt_i[i] : 0; }
    int tsum = v[0] + v[1] + v[2] + v[3];

    int incl = tsum;
#pragma unroll
    for (int off = 1; off < 64; off <<= 1) {
        int x = __shfl_up(incl, off);
        if (lane >= off) incl += x;
    }
    __shared__ int wsum[4];
    if (lane == 63) wsum[wv] = incl;
    __syncthreads();
    int wpre = 0;
    for (int w = 0; w < wv; ++w) wpre += wsum[w];

    int bbase = 0;
    for (int i = 0; i < b; ++i) bbase += blocksum[i];

    int excl = bbase + wpre + incl - tsum;
#pragma unroll
    for (int k = 0; k < 4; ++k) {
        int i = i0 + k;
        if (i < N) base[i] = excl;
        excl += v[k];
    }
}

__global__ __launch_bounds__(256) void k_scatter(
    const int* __restrict__ erow, const int* __restrict__ base,
    int* __restrict__ fill, int* __restrict__ perm, int E)
{
    int e = blockIdx.x * 256 + threadIdx.x;
    if (e < E) {
        int r = erow[e];
        int pos = base[r] + atomicAdd(&fill[r], 1);
        perm[pos] = e;
    }
}

// one wave per node: 16 lanes x float4 cover the 256B edge row, 4 rows in
// flight (jg = lane>>4) + 2x unroll for memory-level parallelism.
__global__ __launch_bounds__(256) void k_agg(
    const float* __restrict__ edge_attr, const int* __restrict__ perm,
    const int* __restrict__ base, const int* __restrict__ cnt_i,
    float* __restrict__ agg, int N)
{
    int tid = threadIdx.x;
    int n = blockIdx.x * 4 + (tid >> 6);
    if (n >= N) return;
    int lane = tid & 63, seg = lane & 15, jg = lane >> 4;
    int s = base[n], c = cnt_i[n];
    float4 acc = make_float4(0.f, 0.f, 0.f, 0.f);
    int j = jg;
    for (; j + 4 < c; j += 8) {
        int e0 = perm[s + j];
        int e1 = perm[s + j + 4];
        float4 a0 = *reinterpret_cast<const float4*>(edge_attr + (size_t)e0 * EDIM + seg * 4);
        float4 a1 = *reinterpret_cast<const float4*>(edge_attr + (size_t)e1 * EDIM + seg * 4);
        acc.x += a0.x + a1.x; acc.y += a0.y + a1.y;
        acc.z += a0.z + a1.z; acc.w += a0.w + a1.w;
    }
    if (j < c) {
        int e0 = perm[s + j];
        float4 a0 = *reinterpret_cast<const float4*>(edge_attr + (size_t)e0 * EDIM + seg * 4);
        acc.x += a0.x; acc.y += a0.y; acc.z += a0.z; acc.w += a0.w;
    }
#pragma unroll
    for (int off = 16; off < 64; off <<= 1) {
        acc.x += __shfl_xor(acc.x, off);
        acc.y += __shfl_xor(acc.y, off);
        acc.z += __shfl_xor(acc.z, off);
        acc.w += __shfl_xor(acc.w, off);
    }
    if (jg == 0)
        *reinterpret_cast<float4*>(agg + (size_t)n * EDIM + seg * 4) = acc;
}

// ---------------------------------------------------------------------------
// Pre-swizzle combined weights [K=192][256] into MFMA B-fragment order,
// split hi/lo bf16.
// ---------------------------------------------------------------------------
__global__ __launch_bounds__(256) void k_prepw(
    const float* __restrict__ node_w, const float* __restrict__ edge_w,
    ushort* __restrict__ whi, ushort* __restrict__ wlo)
{
    int idx = blockIdx.x * 256 + threadIdx.x;
    if (idx >= 16 * 6 * 64 * 8) return;
    int i = idx & 7;
    int l = (idx >> 3) & 63;
    int t2 = idx >> 9;
    int s = t2 % 6;
    int c = t2 / 6;
    int k = s * 32 + (l >> 4) * 8 + i;
    int col = c * 16 + (l & 15);
    float val = (k < NDIM) ? node_w[(size_t)col * NDIM + k]
                           : edge_w[(size_t)col * EDIM + (k - NDIM)];
    ushort hi = f2bf(val);
    ushort lo = f2bf(val - bf2f(hi));
    whi[idx] = hi;
    wlo[idx] = lo;
}

// ---------------------------------------------------------------------------
// q = query @ wq.T + bq; qk[h,:] = sum_d q[h,d]*wk[h*64+d,:]; sb[h] likewise.
// ---------------------------------------------------------------------------
__global__ __launch_bounds__(256) void k_prep(
    const float* __restrict__ query, const float* __restrict__ in_w,
    const float* __restrict__ in_b, float* __restrict__ qk, float* __restrict__ sb)
{
    __shared__ float q_s[DDIM];
    __shared__ float qv[DDIM];
    int tid = threadIdx.x;
    q_s[tid] = query[tid];
    __syncthreads();
    float acc = in_b[tid];
    const float* wq = in_w + (size_t)tid * DDIM;
    for (int i = 0; i < DDIM; ++i) acc += q_s[i] * wq[i];
    qv[tid] = acc;
    __syncthreads();
    for (int h = 0; h < 4; ++h) {
        float a = 0.f;
        for (int d = 0; d < 64; ++d)
            a += qv[h * 64 + d] * in_w[(size_t)(DDIM + h * 64 + d) * DDIM + tid];
        qk[h * DDIM + tid] = a;
    }
    if (tid < 4) {
        float a = 0.f;
        for (int d = 0; d < 64; ++d) a += qv[tid * 64 + d] * in_b[DDIM + tid * 64 + d];
        sb[tid] = a;
    }
}

// ---------------------------------------------------------------------------
// MFMA projection + scores (split-precision bf16, ~f32 accuracy).
// ---------------------------------------------------------------------------
__global__ __launch_bounds__(256) void k_proj_mfma(
    const float* __restrict__ h, const float* __restrict__ agg, const int* __restrict__ cnt_i,
    const ushort* __restrict__ whi, const ushort* __restrict__ wlo,
    const float* __restrict__ node_b, const float* __restrict__ edge_b,
    const float* __restrict__ qk, const float* __restrict__ sb,
    ushort* __restrict__ h_proj_bf, float* __restrict__ scores, int N)
{
    extern __shared__ char smem[];
    uint32_t* A_pk = (uint32_t*)smem;            // [BM][APK_STRIDE]
    ushort*   hpbuf = (ushort*)smem;             // [BM][HPB_STRIDE] (aliased after K-loop)
    __shared__ float ps_s[2][BM][4];
    __shared__ float cnt_s[BM];

    const int tid = threadIdx.x;
    const int n0 = blockIdx.x * BM;

    if (tid < BM) {
        int n = n0 + tid;
        cnt_s[tid] = (n < N) ? (float)cnt_i[n] : 0.f;
    }
    __syncthreads();

    const float4* h4 = reinterpret_cast<const float4*>(h);
#pragma unroll
    for (int it = 0; it < 4; ++it) {
        int idx4 = tid + 256 * it;
        int node = idx4 >> 5;
        int kq = idx4 & 31;
        float4 v = make_float4(0.f, 0.f, 0.f, 0.f);
        if (n0 + node < N) v = h4[(size_t)(n0 + node) * 32 + kq];
        uint32_t* dst = &A_pk[node * APK_STRIDE + kq * 4];
        dst[0] = pack_hilo(v.x); dst[1] = pack_hilo(v.y);
        dst[2] = pack_hilo(v.z); dst[3] = pack_hilo(v.w);
    }
    const float4* a4 = reinterpret_cast<const float4*>(agg);
#pragma unroll
    for (int it = 0; it < 2; ++it) {
        int idx4 = tid + 256 * it;
        int node = idx4 >> 4;
        int kq = idx4 & 15;
        float4 v = make_float4(0.f, 0.f, 0.f, 0.f);
        if (n0 + node < N) v = a4[(size_t)(n0 + node) * 16 + kq];
        float inv = 1.f / fmaxf(cnt_s[node], 1.f);
        uint32_t* dst = &A_pk[node * APK_STRIDE + NDIM + kq * 4];
        dst[0] = pack_hilo(v.x * inv); dst[1] = pack_hilo(v.y * inv);
        dst[2] = pack_hilo(v.z * inv); dst[3] = pack_hilo(v.w * inv);
    }
    __syncthreads();

    const int lane = tid & 63;
    const int w = tid >> 6;
    const int rb = w & 1;
    const int cb = w >> 1;
    const int arow = rb * 16 + (lane & 15);
    const uint32_t* arow_p = &A_pk[arow * APK_STRIDE + (lane >> 4) * 8];

    floatx4 acc[8];
#pragma unroll
    for (int t = 0; t < 8; ++t) acc[t] = 0.f;

#pragma unroll 2
    for (int s = 0; s < 6; ++s) {
        uint32_t au[8];
#pragma unroll
        for (int j = 0; j < 8; ++j) au[j] = arow_p[s * 32 + j];
        short8 ahi, alo;
#pragma unroll
        for (int j = 0; j < 8; ++j) {
            ahi[j] = (short)(au[j] & 0xffffu);
            alo[j] = (short)(au[j] >> 16);
        }
#pragma unroll
        for (int t = 0; t < 8; ++t) {
            size_t boff = ((size_t)((cb * 8 + t) * 6 + s) * 64 + lane) * 8;
            short8 bhi = *reinterpret_cast<const short8*>(whi + boff);
            short8 blo = *reinterpret_cast<const short8*>(wlo + boff);
            acc[t] = __builtin_amdgcn_mfma_f32_16x16x32_bf16(ahi, bhi, acc[t], 0, 0, 0);
            acc[t] = __builtin_amdgcn_mfma_f32_16x16x32_bf16(ahi, blo, acc[t], 0, 0, 0);
            acc[t] = __builtin_amdgcn_mfma_f32_16x16x32_bf16(alo, bhi, acc[t], 0, 0, 0);
        }
    }
    __syncthreads();

    float nb_l[8], eb_l[8];
    float qk_l[4][8];
#pragma unroll
    for (int t = 0; t < 8; ++t) {
        int col = cb * 128 + t * 16 + (lane & 15);
        nb_l[t] = node_b[col];
        eb_l[t] = edge_b[col];
#pragma unroll
        for (int hh = 0; hh < 4; ++hh) qk_l[hh][t] = qk[hh * DDIM + col];
    }
    const int rbase = rb * 16 + (lane >> 4) * 4;
    float fl[4];
#pragma unroll
    for (int r = 0; r < 4; ++r) fl[r] = (cnt_s[rbase + r] >= 0.5f) ? 1.f : 0.f;

    float ph[4][4];
#pragma unroll
    for (int r = 0; r < 4; ++r)
#pragma unroll
        for (int hh = 0; hh < 4; ++hh) ph[r][hh] = 0.f;

#pragma unroll
    for (int t = 0; t < 8; ++t) {
#pragma unroll
        for (int r = 0; r < 4; ++r) {
            float hp = acc[t][r] + nb_l[t] + fl[r] * eb_l[t];
#pragma unroll
            for (int hh = 0; hh < 4; ++hh) ph[r][hh] += hp * qk_l[hh][t];
            hpbuf[(rbase + r) * HPB_STRIDE + cb * 128 + t * 16 + (lane & 15)] = f2bf(hp);
        }
    }

#pragma unroll
    for (int r = 0; r < 4; ++r)
#pragma unroll
        for (int hh = 0; hh < 4; ++hh) {
            float v = ph[r][hh];
            v += __shfl_xor(v, 1); v += __shfl_xor(v, 2);
            v += __shfl_xor(v, 4); v += __shfl_xor(v, 8);
            ph[r][hh] = v;
        }
    if ((lane & 15) == 0) {
#pragma unroll
        for (int r = 0; r < 4; ++r)
#pragma unroll
            for (int hh = 0; hh < 4; ++hh)
                ps_s[cb][rbase + r][hh] = ph[r][hh];
    }
    __syncthreads();

    if (tid < 128) {
        int row = tid >> 2, hh = tid & 3;
        int n = n0 + row;
        if (n < N)
            scores[(size_t)n * 4 + hh] =
                (ps_s[0][row][hh] + ps_s[1][row][hh] + sb[hh]) * 0.125f;
    }

    {
        int row = tid >> 3, seg = tid & 7;
        int n = n0 + row;
        if (n < N) {
#pragma unroll
            for (int q = 0; q < 4; ++q) {
                short8 v = *reinterpret_cast<const short8*>(
                    &hpbuf[row * HPB_STRIDE + seg * 32 + q * 8]);
                *reinterpret_cast<short8*>(
                    &h_proj_bf[(size_t)n * DDIM + seg * 32 + q * 8]) = v;
            }
        }
    }
}

// ---------------------------------------------------------------------------
// Quarter-graph online-softmax pooling partials. Block b: graph b>>2, part b&3.
// ---------------------------------------------------------------------------
__global__ __launch_bounds__(256) void k_pool2(
    const ushort* __restrict__ h_proj_bf, const float* __restrict__ scores,
    const int* __restrict__ batch,
    float* __restrict__ pm, float* __restrict__ pd, float* __restrict__ phb, int N)
{
    __shared__ float sc_s[256 * 4];
    __shared__ float red_s[16];

    const int b = blockIdx.x;
    const int g = b >> 2;
    const int part = b & 3;
    const int tid = threadIdx.x;
    const int lane = tid & 63;
    const int wave = tid >> 6;

    int lo = 0, hi = N;
    while (lo < hi) { int mid = (lo + hi) >> 1; if (batch[mid] < g) lo = mid + 1; else hi = mid; }
    const int s = lo;
    hi = N;
    while (lo < hi) { int mid = (lo + hi) >> 1; if (batch[mid] < g + 1) lo = mid + 1; else hi = mid; }
    const int e = lo;
    const int len = e - s;
    const int cs = s + (len * part) / NSPLIT;
    const int ce = s + (len * (part + 1)) / NSPLIT;

    float m[4], dn[4], hb[4];
#pragma unroll
    for (int hh = 0; hh < 4; ++hh) { m[hh] = -INFINITY; dn[hh] = 0.f; hb[hh] = 0.f; }

    const int h = tid & 3;

    for (int c = cs; c < ce; c += 256) {
        int cn = min(256, ce - c);
        __syncthreads();
        if (tid < cn)
            *reinterpret_cast<float4*>(&sc_s[tid * 4]) =
                *reinterpret_cast<const float4*>(scores + (size_t)(c + tid) * 4);
        __syncthreads();

        float lm = -INFINITY;
        for (int n = tid >> 2; n < cn; n += 64) lm = fmaxf(lm, sc_s[n * 4 + h]);
#pragma unroll
        for (int off = 4; off < 64; off <<= 1) lm = fmaxf(lm, __shfl_xor(lm, off));
        if (lane < 4) red_s[wave * 4 + lane] = lm;
        __syncthreads();

        float nm[4];
#pragma unroll
        for (int hh = 0; hh < 4; ++hh) {
            float cm = fmaxf(fmaxf(red_s[hh], red_s[4 + hh]),
                             fmaxf(red_s[8 + hh], red_s[12 + hh]));
            nm[hh] = fmaxf(m[hh], cm);
            float sc = expf(m[hh] - nm[hh]);
            dn[hh] *= sc; hb[hh] *= sc; m[hh] = nm[hh];
        }
        __syncthreads();

        float mh = (h == 0) ? nm[0] : (h == 1) ? nm[1] : (h == 2) ? nm[2] : nm[3];
        float ld = 0.f;
        for (int idx = tid; idx < cn * 4; idx += 256) {
            float wv = expf(sc_s[idx] - mh);
            sc_s[idx] = wv;
            ld += wv;
        }
#pragma unroll
        for (int off = 4; off < 64; off <<= 1) ld += __shfl_xor(ld, off);
        __syncthreads();
        if (lane < 4) red_s[wave * 4 + lane] = ld;
        __syncthreads();
#pragma unroll
        for (int hh = 0; hh < 4; ++hh)
            dn[hh] += red_s[hh] + red_s[4 + hh] + red_s[8 + hh] + red_s[12 + hh];

#pragma unroll 4
        for (int n = 0; n < cn; ++n) {
            float val = bf2f(h_proj_bf[(size_t)(c + n) * DDIM + tid]);
            float4 w4 = *reinterpret_cast<const float4*>(&sc_s[n * 4]);
            hb[0] += w4.x * val;
            hb[1] += w4.y * val;
            hb[2] += w4.z * val;
            hb[3] += w4.w * val;
        }
    }

    if (tid < 4) { pm[b * 4 + tid] = m[tid]; pd[b * 4 + tid] = dn[tid]; }
#pragma unroll
    for (int hh = 0; hh < 4; ++hh)
        phb[(size_t)(b * 4 + hh) * DDIM + tid] = hb[hh];
}

// ---------------------------------------------------------------------------
// Merge NSPLIT partials + value/output GEMMs. One block per graph.
// ---------------------------------------------------------------------------
__global__ __launch_bounds__(256) void k_out(
    const float* __restrict__ pm, const float* __restrict__ pd, const float* __restrict__ phb,
    const float* __restrict__ in_w, const float* __restrict__ in_b,
    const float* __restrict__ out_w, const float* __restrict__ out_b,
    float* __restrict__ out)
{
    __shared__ float hb_s[4 * DDIM];
    __shared__ float po_s[DDIM];

    const int g = blockIdx.x;
    const int tid = threadIdx.x;
    const int b0 = NSPLIT * g;

    float M[4], dnm[4], sc[NSPLIT][4];
#pragma unroll
    for (int hh = 0; hh < 4; ++hh) {
        float Mh = -INFINITY;
#pragma unroll
        for (int p = 0; p < NSPLIT; ++p) Mh = fmaxf(Mh, pm[(b0 + p) * 4 + hh]);
        M[hh] = Mh;
        float d = 0.f;
#pragma unroll
        for (int p = 0; p < NSPLIT; ++p) {
            float mp = pm[(b0 + p) * 4 + hh];
            float scp = (mp == -INFINITY) ? 0.f : expf(mp - Mh);
            sc[p][hh] = scp;
            d += pd[(b0 + p) * 4 + hh] * scp;
        }
        dnm[hh] = d;
    }
    const float has = (M[0] > -INFINITY) ? 1.f : 0.f;

#pragma unroll
    for (int hh = 0; hh < 4; ++hh) {
        float hb = 0.f;
#pragma unroll
        for (int p = 0; p < NSPLIT; ++p)
            hb += phb[(size_t)((b0 + p) * 4 + hh) * DDIM + tid] * sc[p][hh];
        hb_s[hh * DDIM + tid] = hb / fmaxf(dnm[hh], 1e-30f);
    }
    __syncthreads();

    const int jh = tid >> 6;
    const float* wv_row = in_w + (size_t)(2 * DDIM + tid) * DDIM;
    const float* hbr = &hb_s[jh * DDIM];
    float p = 0.f;
    for (int i = 0; i < DDIM; i += 4) {
        float4 a = *reinterpret_cast<const float4*>(hbr + i);
        float4 bb = *reinterpret_cast<const float4*>(wv_row + i);
        p += a.x * bb.x + a.y * bb.y + a.z * bb.z + a.w * bb.w;
    }
    p = (p + in_b[2 * DDIM + tid]) * has;
    po_s[tid] = p;
    __syncthreads();

    const float* ow_row = out_w + (size_t)tid * DDIM;
    float o = out_b[tid];
    for (int i = 0; i < DDIM; i += 4) {
        float4 a = *reinterpret_cast<const float4*>(&po_s[i]);
        float4 bb = *reinterpret_cast<const float4*>(ow_row + i);
        o += a.x * bb.x + a.y * bb.y + a.z * bb.z + a.w * bb.w;
    }
    out[(size_t)g * DDIM + tid] = o;
}

// ---------------------------------------------------------------------------
extern "C" void kernel_launch(void* const* d_in, const int* in_sizes, int n_in,
                              void* d_out, int out_size, void* d_ws, size_t ws_size,
                              hipStream_t stream) {
    const float* h         = (const float*)d_in[0];
    const int*   edge_idx  = (const int*)d_in[1];
    const float* edge_attr = (const float*)d_in[2];
    const int*   batch     = (const int*)d_in[3];
    const float* node_w    = (const float*)d_in[5];
    const float* node_b    = (const float*)d_in[6];
    const float* edge_w    = (const float*)d_in[7];
    const float* edge_b    = (const float*)d_in[8];
    const float* query     = (const float*)d_in[9];
    const float* in_w      = (const float*)d_in[10];
    const float* in_b      = (const float*)d_in[11];
    const float* out_w     = (const float*)d_in[12];
    const float* out_b     = (const float*)d_in[13];
    float* out = (float*)d_out;

    const int N = in_sizes[0] / NDIM;
    const int E = in_sizes[2] / EDIM;
    const int G = out_size / DDIM;
    const int nblk1 = (N + 1023) / 1024;
    const int NSWZ = 16 * 6 * 64 * 8;   // 49152

    char* ws = (char*)d_ws;
    size_t off = 0;
    auto alloc = [&](size_t bytes) { void* p = ws + off; off += (bytes + 255) & ~(size_t)255; return p; };

    int*    cnt_i      = (int*)alloc((size_t)N * 4 * 2);
    int*    fill       = cnt_i + N;
    int*    base       = (int*)alloc((size_t)N * 4);
    int*    perm       = (int*)alloc((size_t)E * 4);
    int*    blocksum   = (int*)alloc((size_t)nblk1 * 4);
    float*  agg        = (float*)alloc((size_t)N * EDIM * 4);
    ushort* h_proj_bf  = (ushort*)alloc((size_t)N * DDIM * 2);
    float*  scores     = (float*)alloc((size_t)N * 4 * 4);
    ushort* whi        = (ushort*)alloc((size_t)NSWZ * 2);
    ushort* wlo        = (ushort*)alloc((size_t)NSWZ * 2);
    float*  qk         = (float*)alloc(4 * DDIM * 4);
    float*  sb         = (float*)alloc(16 * 4);
    float*  pm         = (float*)alloc((size_t)NSPLIT * G * 4 * 4);
    float*  pd         = (float*)alloc((size_t)NSPLIT * G * 4 * 4);
    float*  phb        = (float*)alloc((size_t)NSPLIT * G * 4 * DDIM * 4);

    k_zero<<<(2 * N + 255) / 256, 256, 0, stream>>>(cnt_i, 2 * N);

    k_hist<<<(E + 255) / 256, 256, 0, stream>>>(edge_idx, cnt_i, E);
    k_scan1<<<nblk1, 256, 0, stream>>>(cnt_i, blocksum, N);
    k_scan3<<<nblk1, 256, 0, stream>>>(cnt_i, blocksum, base, N);
    k_scatter<<<(E + 255) / 256, 256, 0, stream>>>(edge_idx, base, fill, perm, E);
    k_agg<<<(N + 3) / 4, 256, 0, stream>>>(edge_attr, perm, base, cnt_i, agg, N);

    k_prepw<<<(NSWZ + 255) / 256, 256, 0, stream>>>(node_w, edge_w, whi, wlo);
    k_prep<<<1, 256, 0, stream>>>(query, in_w, in_b, qk, sb);

    const int ldsA = BM * APK_STRIDE * 4;   // 26112 B dynamic LDS
    k_proj_mfma<<<(N + BM - 1) / BM, 256, ldsA, stream>>>(
        h, agg, cnt_i, whi, wlo, node_b, edge_b, qk, sb, h_proj_bf, scores, N);

    k_pool2<<<NSPLIT * G, 256, 0, stream>>>(h_proj_bf, scores, batch, pm, pd, phb, N);
    k_out<<<G, 256, 0, stream>>>(pm, pd, phb, in_w, in_b, out_w, out_b, out);
}

// Round 5
// 239.433 us; speedup vs baseline: 4.1675x; 1.0582x over previous
//
#include <hip/hip_runtime.h>
#include <hip/hip_bf16.h>
#include <math.h>

#define NDIM 128
#define EDIM 64
#define DDIM 256
#define BM 32             // nodes per k_proj block (one 32-row MFMA strip)
#define APK_STRIDE 204    // u32 stride for A_pk rows (16B aligned, 4-way-bank ok)
#define HPB_STRIDE 264    // ushort stride for hpbuf rows
#define NSPLIT 4          // pool partials per graph
#define NSWZ (8 * 12 * 64 * 8)   // swizzled B elements: 8 col-tiles x 12 k-steps

typedef __attribute__((ext_vector_type(8))) short short8;
typedef __attribute__((ext_vector_type(16))) float floatx16;

__device__ inline ushort f2bf(float x) {
    uint32_t u = __float_as_uint(x);
    uint32_t r = (u + 0x7fff + ((u >> 16) & 1)) >> 16;
    return (ushort)r;
}
__device__ inline float bf2f(ushort h) { return __uint_as_float(((uint32_t)h) << 16); }
__device__ inline uint32_t pack_hilo(float x) {
    ushort hi = f2bf(x);
    ushort lo = f2bf(x - bf2f(hi));
    return (uint32_t)hi | ((uint32_t)lo << 16);
}

// ---------------------------------------------------------------------------
// Fused setup: [0,ZBLK) zero cnt_i+fill; [ZBLK,ZBLK+192) B pre-swizzle;
// last block: q/qk/sb prep.
// B layout for 32x32x16: whi[(((t2*12)+s)*64+l)*8+i], k=s*16+(l>>5)*8+i,
// col=t2*32+(l&31). A/B k-slot convention consistent by construction.
// ---------------------------------------------------------------------------
__global__ __launch_bounds__(256) void k_setup(
    int* __restrict__ cnt_i, int n_zero, int ZBLK,
    const float* __restrict__ node_w, const float* __restrict__ edge_w,
    ushort* __restrict__ whi, ushort* __restrict__ wlo,
    const float* __restrict__ query, const float* __restrict__ in_w,
    const float* __restrict__ in_b, float* __restrict__ qk, float* __restrict__ sb)
{
    const int tid = threadIdx.x;
    int b = blockIdx.x;
    if (b < ZBLK) {
        int i = b * 256 + tid;
        if (i < n_zero) cnt_i[i] = 0;
        return;
    }
    b -= ZBLK;
    if (b < 192) {
        int idx = b * 256 + tid;      // < 49152 exactly
        int i = idx & 7;
        int l = (idx >> 3) & 63;
        int rest = idx >> 9;          // 0..95
        int s = rest % 12;
        int t2 = rest / 12;
        int k = s * 16 + (l >> 5) * 8 + i;
        int col = t2 * 32 + (l & 31);
        float val = (k < NDIM) ? node_w[(size_t)col * NDIM + k]
                               : edge_w[(size_t)col * EDIM + (k - NDIM)];
        ushort hi = f2bf(val);
        ushort lo = f2bf(val - bf2f(hi));
        whi[idx] = hi;
        wlo[idx] = lo;
        return;
    }
    // prep block
    __shared__ float q_s[DDIM];
    __shared__ float qv[DDIM];
    q_s[tid] = query[tid];
    __syncthreads();
    float acc = in_b[tid];
    const float* wq = in_w + (size_t)tid * DDIM;
    for (int i = 0; i < DDIM; ++i) acc += q_s[i] * wq[i];
    qv[tid] = acc;
    __syncthreads();
    for (int h = 0; h < 4; ++h) {
        float a = 0.f;
        for (int d = 0; d < 64; ++d)
            a += qv[h * 64 + d] * in_w[(size_t)(DDIM + h * 64 + d) * DDIM + tid];
        qk[h * DDIM + tid] = a;
    }
    if (tid < 4) {
        float a = 0.f;
        for (int d = 0; d < 64; ++d) a += qv[tid * 64 + d] * in_b[DDIM + tid * 64 + d];
        sb[tid] = a;
    }
}

// ---------------------------------------------------------------------------
// Edge binning pipeline: hist -> scan -> scatter(perm) -> segmented reduce
// ---------------------------------------------------------------------------
__global__ __launch_bounds__(256) void k_hist(
    const int* __restrict__ erow, int* __restrict__ cnt_i, int E)
{
    int e = blockIdx.x * 256 + threadIdx.x;
    if (e < E) atomicAdd(&cnt_i[erow[e]], 1);
}

__global__ __launch_bounds__(256) void k_scan1(
    const int* __restrict__ cnt_i, int* __restrict__ blocksum, int N)
{
    int tid = threadIdx.x;
    int i0 = blockIdx.x * 1024 + tid * 4;
    int s = 0;
#pragma unroll
    for (int k = 0; k < 4; ++k) { int i = i0 + k; if (i < N) s += cnt_i[i]; }
#pragma unroll
    for (int off = 1; off < 64; off <<= 1) s += __shfl_xor(s, off);
    __shared__ int ws4[4];
    if ((tid & 63) == 0) ws4[tid >> 6] = s;
    __syncthreads();
    if (tid == 0) blocksum[blockIdx.x] = ws4[0] + ws4[1] + ws4[2] + ws4[3];
}

__global__ __launch_bounds__(256) void k_scan3(
    const int* __restrict__ cnt_i, const int* __restrict__ blocksum,
    int* __restrict__ base, int N)
{
    const int tid = threadIdx.x;
    const int lane = tid & 63;
    const int wv = tid >> 6;
    const int b = blockIdx.x;
    const int i0 = b * 1024 + tid * 4;

    int v[4];
#pragma unroll
    for (int k = 0; k < 4; ++k) { int i = i0 + k; v[k] = (i < N) ? cnt_i[i] : 0; }
    int tsum = v[0] + v[1] + v[2] + v[3];

    int incl = tsum;
#pragma unroll
    for (int off = 1; off < 64; off <<= 1) {
        int x = __shfl_up(incl, off);
        if (lane >= off) incl += x;
    }
    __shared__ int wsum[4];
    if (lane == 63) wsum[wv] = incl;
    __syncthreads();
    int wpre = 0;
    for (int w = 0; w < wv; ++w) wpre += wsum[w];

    // wave-parallel blocksum prefix (b <= 48 < 64 lanes)
    int bb = (lane < b) ? blocksum[lane] : 0;
#pragma unroll
    for (int off = 1; off < 64; off <<= 1) bb += __shfl_xor(bb, off);

    int excl = bb + wpre + incl - tsum;
#pragma unroll
    for (int k = 0; k < 4; ++k) {
        int i = i0 + k;
        if (i < N) base[i] = excl;
        excl += v[k];
    }
}

__global__ __launch_bounds__(256) void k_scatter(
    const int* __restrict__ erow, const int* __restrict__ base,
    int* __restrict__ fill, int* __restrict__ perm, int E)
{
    int e = blockIdx.x * 256 + threadIdx.x;
    if (e < E) {
        int r = erow[e];
        int pos = base[r] + atomicAdd(&fill[r], 1);
        perm[pos] = e;
    }
}

// one wave per node: 16 lanes x float4 cover the 256B edge row, 4 rows in
// flight (jg) x 4-deep unroll for memory-level parallelism.
__global__ __launch_bounds__(256) void k_agg(
    const float* __restrict__ edge_attr, const int* __restrict__ perm,
    const int* __restrict__ base, const int* __restrict__ cnt_i,
    float* __restrict__ agg, int N)
{
    int tid = threadIdx.x;
    int n = blockIdx.x * 4 + (tid >> 6);
    if (n >= N) return;
    int lane = tid & 63, seg = lane & 15, jg = lane >> 4;
    int s = base[n], c = cnt_i[n];
    float4 acc = make_float4(0.f, 0.f, 0.f, 0.f);
    int j = jg;
    for (; j + 12 < c; j += 16) {
        int e0 = perm[s + j];
        int e1 = perm[s + j + 4];
        int e2 = perm[s + j + 8];
        int e3 = perm[s + j + 12];
        float4 a0 = *reinterpret_cast<const float4*>(edge_attr + (size_t)e0 * EDIM + seg * 4);
        float4 a1 = *reinterpret_cast<const float4*>(edge_attr + (size_t)e1 * EDIM + seg * 4);
        float4 a2 = *reinterpret_cast<const float4*>(edge_attr + (size_t)e2 * EDIM + seg * 4);
        float4 a3 = *reinterpret_cast<const float4*>(edge_attr + (size_t)e3 * EDIM + seg * 4);
        acc.x += (a0.x + a1.x) + (a2.x + a3.x);
        acc.y += (a0.y + a1.y) + (a2.y + a3.y);
        acc.z += (a0.z + a1.z) + (a2.z + a3.z);
        acc.w += (a0.w + a1.w) + (a2.w + a3.w);
    }
    for (; j < c; j += 4) {
        int e0 = perm[s + j];
        float4 a0 = *reinterpret_cast<const float4*>(edge_attr + (size_t)e0 * EDIM + seg * 4);
        acc.x += a0.x; acc.y += a0.y; acc.z += a0.z; acc.w += a0.w;
    }
#pragma unroll
    for (int off = 16; off < 64; off <<= 1) {
        acc.x += __shfl_xor(acc.x, off);
        acc.y += __shfl_xor(acc.y, off);
        acc.z += __shfl_xor(acc.z, off);
        acc.w += __shfl_xor(acc.w, off);
    }
    if (jg == 0)
        *reinterpret_cast<float4*>(agg + (size_t)n * EDIM + seg * 4) = acc;
}

// ---------------------------------------------------------------------------
// MFMA projection + scores, 32x32x16 bf16 split-precision (~f32 accuracy).
// One 32-row strip per block; wave w owns col-tiles {2w, 2w+1} (64 cols).
// B-fragment L2 traffic: 96 KB/block (4x less than 16x16x32 version).
// ---------------------------------------------------------------------------
__global__ __launch_bounds__(256) void k_proj_mfma(
    const float* __restrict__ h, const float* __restrict__ agg, const int* __restrict__ cnt_i,
    const ushort* __restrict__ whi, const ushort* __restrict__ wlo,
    const float* __restrict__ node_b, const float* __restrict__ edge_b,
    const float* __restrict__ qk, const float* __restrict__ sb,
    ushort* __restrict__ h_proj_bf, float* __restrict__ scores, int N)
{
    extern __shared__ char smem[];
    uint32_t* A_pk = (uint32_t*)smem;            // [BM][APK_STRIDE] u32
    ushort*   hpbuf = (ushort*)smem;             // [BM][HPB_STRIDE] (alias after K-loop)
    __shared__ float qk_s[4 * DDIM];
    __shared__ float cnt_s[BM];
    __shared__ float sb_s[4];

    const int tid = threadIdx.x;
    const int n0 = blockIdx.x * BM;

    if (tid < BM) {
        int n = n0 + tid;
        cnt_s[tid] = (n < N) ? (float)cnt_i[n] : 0.f;
    }
    if (tid < 4) sb_s[tid] = sb[tid];
    for (int i = tid; i < 4 * DDIM; i += 256) qk_s[i] = qk[i];
    __syncthreads();

    // stage h (32 x 128 f32 -> packed hi|lo u32)
    const float4* h4 = reinterpret_cast<const float4*>(h);
#pragma unroll
    for (int it = 0; it < 4; ++it) {
        int idx4 = tid + 256 * it;
        int node = idx4 >> 5;
        int kq = idx4 & 31;
        float4 v = make_float4(0.f, 0.f, 0.f, 0.f);
        if (n0 + node < N) v = h4[(size_t)(n0 + node) * 32 + kq];
        uint32_t* dst = &A_pk[node * APK_STRIDE + kq * 4];
        dst[0] = pack_hilo(v.x); dst[1] = pack_hilo(v.y);
        dst[2] = pack_hilo(v.z); dst[3] = pack_hilo(v.w);
    }
    // stage agg/cnt (32 x 64)
    const float4* a4 = reinterpret_cast<const float4*>(agg);
#pragma unroll
    for (int it = 0; it < 2; ++it) {
        int idx4 = tid + 256 * it;
        int node = idx4 >> 4;
        int kq = idx4 & 15;
        float4 v = make_float4(0.f, 0.f, 0.f, 0.f);
        if (n0 + node < N) v = a4[(size_t)(n0 + node) * 16 + kq];
        float inv = 1.f / fmaxf(cnt_s[node], 1.f);
        uint32_t* dst = &A_pk[node * APK_STRIDE + NDIM + kq * 4];
        dst[0] = pack_hilo(v.x * inv); dst[1] = pack_hilo(v.y * inv);
        dst[2] = pack_hilo(v.z * inv); dst[3] = pack_hilo(v.w * inv);
    }
    __syncthreads();

    const int lane = tid & 63;
    const int w = tid >> 6;
    const int kg8 = (lane >> 5) * 8;
    const uint32_t* arow_p = &A_pk[(lane & 31) * APK_STRIDE];

    floatx16 acc[2];
#pragma unroll
    for (int t = 0; t < 2; ++t) acc[t] = 0.f;

#pragma unroll 4
    for (int s = 0; s < 12; ++s) {
        uint32_t au[8];
        *reinterpret_cast<uint4*>(&au[0]) = *reinterpret_cast<const uint4*>(&arow_p[s * 16 + kg8]);
        *reinterpret_cast<uint4*>(&au[4]) = *reinterpret_cast<const uint4*>(&arow_p[s * 16 + kg8 + 4]);
        short8 ahi, alo;
#pragma unroll
        for (int j = 0; j < 8; ++j) {
            ahi[j] = (short)(au[j] & 0xffffu);
            alo[j] = (short)(au[j] >> 16);
        }
#pragma unroll
        for (int t = 0; t < 2; ++t) {
            size_t boff = ((size_t)(((w * 2 + t) * 12 + s) * 64) + lane) * 8;
            short8 bhi = *reinterpret_cast<const short8*>(whi + boff);
            short8 blo = *reinterpret_cast<const short8*>(wlo + boff);
            acc[t] = __builtin_amdgcn_mfma_f32_32x32x16_bf16(ahi, bhi, acc[t], 0, 0, 0);
            acc[t] = __builtin_amdgcn_mfma_f32_32x32x16_bf16(ahi, blo, acc[t], 0, 0, 0);
            acc[t] = __builtin_amdgcn_mfma_f32_32x32x16_bf16(alo, bhi, acc[t], 0, 0, 0);
        }
    }
    __syncthreads();   // A_pk reads done; hpbuf may alias

    // epilogue: bias + edge bias, write hp rows to LDS
#pragma unroll
    for (int t = 0; t < 2; ++t) {
        int colt = (w * 2 + t) * 32 + (lane & 31);
        float nb = node_b[colt];
        float eb = edge_b[colt];
#pragma unroll
        for (int r = 0; r < 16; ++r) {
            int row = (r & 3) + 8 * (r >> 2) + 4 * (lane >> 5);
            float fl = (cnt_s[row] >= 0.5f) ? 1.f : 0.f;
            float hp = acc[t][r] + nb + fl * eb;
            hpbuf[row * HPB_STRIDE + colt] = f2bf(hp);
        }
    }
    __syncthreads();

    // score pass + coalesced bf16 h_proj store (row = tid>>3, 8 lanes/row)
    {
        int row = tid >> 3, seg = tid & 7;
        int n = n0 + row;
        float s0 = 0.f, s1 = 0.f, s2 = 0.f, s3 = 0.f;
#pragma unroll
        for (int q = 0; q < 4; ++q) {
            short8 v = *reinterpret_cast<const short8*>(
                &hpbuf[row * HPB_STRIDE + seg * 32 + q * 8]);
#pragma unroll
            for (int jj = 0; jj < 8; ++jj) {
                float hv = bf2f((ushort)v[jj]);
                int dim = seg * 32 + q * 8 + jj;
                s0 += hv * qk_s[0 * DDIM + dim];
                s1 += hv * qk_s[1 * DDIM + dim];
                s2 += hv * qk_s[2 * DDIM + dim];
                s3 += hv * qk_s[3 * DDIM + dim];
            }
            if (n < N)
                *reinterpret_cast<short8*>(
                    &h_proj_bf[(size_t)n * DDIM + seg * 32 + q * 8]) = v;
        }
#pragma unroll
        for (int off = 1; off < 8; off <<= 1) {
            s0 += __shfl_xor(s0, off);
            s1 += __shfl_xor(s1, off);
            s2 += __shfl_xor(s2, off);
            s3 += __shfl_xor(s3, off);
        }
        if (seg == 0 && n < N) {
            scores[(size_t)n * 4 + 0] = (s0 + sb_s[0]) * 0.125f;
            scores[(size_t)n * 4 + 1] = (s1 + sb_s[1]) * 0.125f;
            scores[(size_t)n * 4 + 2] = (s2 + sb_s[2]) * 0.125f;
            scores[(size_t)n * 4 + 3] = (s3 + sb_s[3]) * 0.125f;
        }
    }
}

// ---------------------------------------------------------------------------
// Quarter-graph online-softmax pooling partials. Block b: graph b>>2, part b&3.
// hbar: wave = node, lane owns 4 dims (ushort4 8B loads), 4 nodes/iter.
// ---------------------------------------------------------------------------
__global__ __launch_bounds__(256) void k_pool2(
    const ushort* __restrict__ h_proj_bf, const float* __restrict__ scores,
    const int* __restrict__ batch,
    float* __restrict__ pm, float* __restrict__ pd, float* __restrict__ phb, int N)
{
    __shared__ float sc_s[256 * 4];
    __shared__ float red_s[16];
    __shared__ float red[4][4][DDIM];   // [node-group][head][dim] 16KB

    const int b = blockIdx.x;
    const int g = b >> 2;
    const int part = b & 3;
    const int tid = threadIdx.x;
    const int lane = tid & 63;
    const int wave = tid >> 6;
    const int ng = tid >> 6;
    const int d0 = (tid & 63) * 4;

    int lo = 0, hi = N;
    while (lo < hi) { int mid = (lo + hi) >> 1; if (batch[mid] < g) lo = mid + 1; else hi = mid; }
    const int s = lo;
    hi = N;
    while (lo < hi) { int mid = (lo + hi) >> 1; if (batch[mid] < g + 1) lo = mid + 1; else hi = mid; }
    const int e = lo;
    const int len = e - s;
    const int cs = s + (len * part) / NSPLIT;
    const int ce = s + (len * (part + 1)) / NSPLIT;

    float m[4], dn[4];
    float hbv[4][4];
#pragma unroll
    for (int hh = 0; hh < 4; ++hh) {
        m[hh] = -INFINITY; dn[hh] = 0.f;
#pragma unroll
        for (int d = 0; d < 4; ++d) hbv[hh][d] = 0.f;
    }

    const int h = tid & 3;

    for (int c = cs; c < ce; c += 256) {
        int cn = min(256, ce - c);
        __syncthreads();
        if (tid < cn)
            *reinterpret_cast<float4*>(&sc_s[tid * 4]) =
                *reinterpret_cast<const float4*>(scores + (size_t)(c + tid) * 4);
        __syncthreads();

        float lm = -INFINITY;
        for (int n = tid >> 2; n < cn; n += 64) lm = fmaxf(lm, sc_s[n * 4 + h]);
#pragma unroll
        for (int off = 4; off < 64; off <<= 1) lm = fmaxf(lm, __shfl_xor(lm, off));
        if (lane < 4) red_s[wave * 4 + lane] = lm;
        __syncthreads();

        float nm[4];
#pragma unroll
        for (int hh = 0; hh < 4; ++hh) {
            float cm = fmaxf(fmaxf(red_s[hh], red_s[4 + hh]),
                             fmaxf(red_s[8 + hh], red_s[12 + hh]));
            nm[hh] = fmaxf(m[hh], cm);
            float sc = expf(m[hh] - nm[hh]);   // m=-inf first chunk -> 0
            dn[hh] *= sc;
#pragma unroll
            for (int d = 0; d < 4; ++d) hbv[hh][d] *= sc;
            m[hh] = nm[hh];
        }
        __syncthreads();

        float mh = (h == 0) ? nm[0] : (h == 1) ? nm[1] : (h == 2) ? nm[2] : nm[3];
        float ld = 0.f;
        for (int idx = tid; idx < cn * 4; idx += 256) {
            float wv = expf(sc_s[idx] - mh);
            sc_s[idx] = wv;
            ld += wv;
        }
#pragma unroll
        for (int off = 4; off < 64; off <<= 1) ld += __shfl_xor(ld, off);
        __syncthreads();
        if (lane < 4) red_s[wave * 4 + lane] = ld;
        __syncthreads();
#pragma unroll
        for (int hh = 0; hh < 4; ++hh)
            dn[hh] += red_s[hh] + red_s[4 + hh] + red_s[8 + hh] + red_s[12 + hh];

        // hbar: 4 nodes per iteration, 8B ushort4 loads
#pragma unroll 2
        for (int nb = 0; nb < cn; nb += 4) {
            int ln = nb + ng;
            bool valid = ln < cn;
            float4 w4 = make_float4(0.f, 0.f, 0.f, 0.f);
            ushort4 hv = make_ushort4(0, 0, 0, 0);
            if (valid) {
                w4 = *reinterpret_cast<const float4*>(&sc_s[ln * 4]);
                hv = *reinterpret_cast<const ushort4*>(
                    &h_proj_bf[(size_t)(c + ln) * DDIM + d0]);
            }
            float vx = bf2f(hv.x), vy = bf2f(hv.y), vz = bf2f(hv.z), vw = bf2f(hv.w);
            hbv[0][0] += w4.x * vx; hbv[1][0] += w4.y * vx; hbv[2][0] += w4.z * vx; hbv[3][0] += w4.w * vx;
            hbv[0][1] += w4.x * vy; hbv[1][1] += w4.y * vy; hbv[2][1] += w4.z * vy; hbv[3][1] += w4.w * vy;
            hbv[0][2] += w4.x * vz; hbv[1][2] += w4.y * vz; hbv[2][2] += w4.z * vz; hbv[3][2] += w4.w * vz;
            hbv[0][3] += w4.x * vw; hbv[1][3] += w4.y * vw; hbv[2][3] += w4.z * vw; hbv[3][3] += w4.w * vw;
        }
    }

    __syncthreads();
#pragma unroll
    for (int hh = 0; hh < 4; ++hh)
#pragma unroll
        for (int d = 0; d < 4; ++d)
            red[ng][hh][d0 + d] = hbv[hh][d];
    __syncthreads();

    if (tid < 4) { pm[b * 4 + tid] = m[tid]; pd[b * 4 + tid] = dn[tid]; }
#pragma unroll
    for (int hh = 0; hh < 4; ++hh)
        phb[(size_t)(b * 4 + hh) * DDIM + tid] =
            red[0][hh][tid] + red[1][hh][tid] + red[2][hh][tid] + red[3][hh][tid];
}

// ---------------------------------------------------------------------------
// Merge NSPLIT partials + value/output GEMMs. One block per graph.
// ---------------------------------------------------------------------------
__global__ __launch_bounds__(256) void k_out(
    const float* __restrict__ pm, const float* __restrict__ pd, const float* __restrict__ phb,
    const float* __restrict__ in_w, const float* __restrict__ in_b,
    const float* __restrict__ out_w, const float* __restrict__ out_b,
    float* __restrict__ out)
{
    __shared__ float hb_s[4 * DDIM];
    __shared__ float po_s[DDIM];

    const int g = blockIdx.x;
    const int tid = threadIdx.x;
    const int b0 = NSPLIT * g;

    float M[4], dnm[4], sc[NSPLIT][4];
#pragma unroll
    for (int hh = 0; hh < 4; ++hh) {
        float Mh = -INFINITY;
#pragma unroll
        for (int p = 0; p < NSPLIT; ++p) Mh = fmaxf(Mh, pm[(b0 + p) * 4 + hh]);
        M[hh] = Mh;
        float d = 0.f;
#pragma unroll
        for (int p = 0; p < NSPLIT; ++p) {
            float mp = pm[(b0 + p) * 4 + hh];
            float scp = (mp == -INFINITY) ? 0.f : expf(mp - Mh);
            sc[p][hh] = scp;
            d += pd[(b0 + p) * 4 + hh] * scp;
        }
        dnm[hh] = d;
    }
    const float has = (M[0] > -INFINITY) ? 1.f : 0.f;

#pragma unroll
    for (int hh = 0; hh < 4; ++hh) {
        float hb = 0.f;
#pragma unroll
        for (int p = 0; p < NSPLIT; ++p)
            hb += phb[(size_t)((b0 + p) * 4 + hh) * DDIM + tid] * sc[p][hh];
        hb_s[hh * DDIM + tid] = hb / fmaxf(dnm[hh], 1e-30f);
    }
    __syncthreads();

    const int jh = tid >> 6;
    const float* wv_row = in_w + (size_t)(2 * DDIM + tid) * DDIM;
    const float* hbr = &hb_s[jh * DDIM];
    float p = 0.f;
    for (int i = 0; i < DDIM; i += 4) {
        float4 a = *reinterpret_cast<const float4*>(hbr + i);
        float4 bb = *reinterpret_cast<const float4*>(wv_row + i);
        p += a.x * bb.x + a.y * bb.y + a.z * bb.z + a.w * bb.w;
    }
    p = (p + in_b[2 * DDIM + tid]) * has;
    po_s[tid] = p;
    __syncthreads();

    const float* ow_row = out_w + (size_t)tid * DDIM;
    float o = out_b[tid];
    for (int i = 0; i < DDIM; i += 4) {
        float4 a = *reinterpret_cast<const float4*>(&po_s[i]);
        float4 bb = *reinterpret_cast<const float4*>(ow_row + i);
        o += a.x * bb.x + a.y * bb.y + a.z * bb.z + a.w * bb.w;
    }
    out[(size_t)g * DDIM + tid] = o;
}

// ---------------------------------------------------------------------------
extern "C" void kernel_launch(void* const* d_in, const int* in_sizes, int n_in,
                              void* d_out, int out_size, void* d_ws, size_t ws_size,
                              hipStream_t stream) {
    const float* h         = (const float*)d_in[0];
    const int*   edge_idx  = (const int*)d_in[1];
    const float* edge_attr = (const float*)d_in[2];
    const int*   batch     = (const int*)d_in[3];
    const float* node_w    = (const float*)d_in[5];
    const float* node_b    = (const float*)d_in[6];
    const float* edge_w    = (const float*)d_in[7];
    const float* edge_b    = (const float*)d_in[8];
    const float* query     = (const float*)d_in[9];
    const float* in_w      = (const float*)d_in[10];
    const float* in_b      = (const float*)d_in[11];
    const float* out_w     = (const float*)d_in[12];
    const float* out_b     = (const float*)d_in[13];
    float* out = (float*)d_out;

    const int N = in_sizes[0] / NDIM;
    const int E = in_sizes[2] / EDIM;
    const int G = out_size / DDIM;
    const int nblk1 = (N + 1023) / 1024;

    char* ws = (char*)d_ws;
    size_t off = 0;
    auto alloc = [&](size_t bytes) { void* p = ws + off; off += (bytes + 255) & ~(size_t)255; return p; };

    int*    cnt_i      = (int*)alloc((size_t)N * 4 * 2);   // cnt_i + fill adjacent
    int*    fill       = cnt_i + N;
    int*    base       = (int*)alloc((size_t)N * 4);
    int*    perm       = (int*)alloc((size_t)E * 4);
    int*    blocksum   = (int*)alloc((size_t)nblk1 * 4);
    float*  agg        = (float*)alloc((size_t)N * EDIM * 4);
    ushort* h_proj_bf  = (ushort*)alloc((size_t)N * DDIM * 2);
    float*  scores     = (float*)alloc((size_t)N * 4 * 4);
    ushort* whi        = (ushort*)alloc((size_t)NSWZ * 2);
    ushort* wlo        = (ushort*)alloc((size_t)NSWZ * 2);
    float*  qk         = (float*)alloc(4 * DDIM * 4);
    float*  sb         = (float*)alloc(16 * 4);
    float*  pm         = (float*)alloc((size_t)NSPLIT * G * 4 * 4);
    float*  pd         = (float*)alloc((size_t)NSPLIT * G * 4 * 4);
    float*  phb        = (float*)alloc((size_t)NSPLIT * G * 4 * DDIM * 4);

    const int ZBLK = (2 * N + 255) / 256;
    k_setup<<<ZBLK + 192 + 1, 256, 0, stream>>>(
        cnt_i, 2 * N, ZBLK, node_w, edge_w, whi, wlo, query, in_w, in_b, qk, sb);

    k_hist<<<(E + 255) / 256, 256, 0, stream>>>(edge_idx, cnt_i, E);
    k_scan1<<<nblk1, 256, 0, stream>>>(cnt_i, blocksum, N);
    k_scan3<<<nblk1, 256, 0, stream>>>(cnt_i, blocksum, base, N);
    k_scatter<<<(E + 255) / 256, 256, 0, stream>>>(edge_idx, base, fill, perm, E);
    k_agg<<<(N + 3) / 4, 256, 0, stream>>>(edge_attr, perm, base, cnt_i, agg, N);

    const int ldsA = BM * APK_STRIDE * 4;   // 26112 B dynamic LDS
    k_proj_mfma<<<(N + BM - 1) / BM, 256, ldsA, stream>>>(
        h, agg, cnt_i, whi, wlo, node_b, edge_b, qk, sb, h_proj_bf, scores, N);

    k_pool2<<<NSPLIT * G, 256, 0, stream>>>(h_proj_bf, scores, batch, pm, pd, phb, N);
    k_out<<<G, 256, 0, stream>>>(pm, pd, phb, in_w, in_b, out_w, out_b, out);
}